// Round 11
// baseline (992.113 us; speedup 1.0000x reference)
//
#include <hip/hip_runtime.h>
#include <stdint.h>

#define BATCH 512
#define MAXZ 3

// ---- workspace layout (bytes) ----
static const size_t OFF_W2P  = 0;          // 25*128*4 u32
static const size_t OFF_W3P  = 51200;
static const size_t OFF_W4P  = 69632;
static const size_t OFF_FCP  = 88064;
static const size_t OFF_STAT = 219136;     // mean1 f32[512]@0; zcnt int[512]@8192; zlist int[512*3]@10240
static const size_t OFF_B1P  = 235520;     // 512*784*16
static const size_t OFF_H2   = 6658048;    // 512*144*128*2 u16 counts (exact)
static const size_t OFF_B2P  = 44406784;
static const size_t OFF_H3   = 45586432;   // 512*100*128*2 u16
static const size_t OFF_B3P  = 71800832;
static const size_t OFF_H4   = 72620032;   // 512*16*128*2 u16
static const size_t OFF_BXP  = 76814336;
// end ~76.9 MB

// Numerics model (validated r8-r10, absmax=0): conv1 = np.einsum f32 SSE2
// order (separately-rounded mul/add); means = numpy pairwise-f32; sign(0)
// ties -> zlist fixup in conv2; binary layers exact integer xnor-popcount.
// Counts fit u16 exactly; u16->f32 conversion is exact => identical decisions.

__device__ inline float mulr(float a, float b) {
    float t = a * b;
    asm volatile("" : "+v"(t));
    return t;
}

// chained xor-popcount accumulate: LLVM folds add(ctpop(x),acc) -> v_bcnt_u32_b32
__device__ inline void xp4(int& acc, uint4 a, uint4 b) {
    acc += __popc(a.x ^ b.x);
    acc += __popc(a.y ^ b.y);
    acc += __popc(a.z ^ b.z);
    acc += __popc(a.w ^ b.w);
}

// einsum SSE2-order 25-tap dot + relu, separately-rounded mul/add (no FMA).
__device__ inline float einsum25(const float* __restrict__ patch,
                                 const float* __restrict__ wr) {
#pragma clang fp contract(off)
    float l0 = wr[0] * patch[0];
    float l1 = wr[1] * patch[1];
    float l2 = wr[2] * patch[2];
    float l3 = wr[3] * patch[3];
#pragma unroll
    for (int t = 1; t < 6; ++t) {
        l0 += wr[4 * t + 0] * patch[4 * t + 0];
        l1 += wr[4 * t + 1] * patch[4 * t + 1];
        l2 += wr[4 * t + 2] * patch[4 * t + 2];
        l3 += wr[4 * t + 3] * patch[4 * t + 3];
    }
    float acc = (l0 + l1) + (l2 + l3);
    acc += wr[24] * patch[24];
    return acc > 0.f ? acc : 0.f;
}

// ---------------- weight packing ----------------
__global__ void pack_conv_w(const float* __restrict__ w, uint32_t* __restrict__ wp, int taps) {
    int idx = blockIdx.x * 256 + threadIdx.x;
    if (idx >= 128 * taps) return;
    int oc = idx / taps, t = idx - oc * taps;
    uint32_t words[4] = {0u, 0u, 0u, 0u};
    for (int ic = 0; ic < 128; ++ic) {
        float v = w[(size_t)(oc * 128 + ic) * taps + t];
        if (v > 0.f) words[ic >> 5] |= 1u << (ic & 31);
    }
#pragma unroll
    for (int k = 0; k < 4; ++k) wp[((size_t)t * 128 + oc) * 4 + k] = words[k];
}

__global__ void pack_fc_w(const float* __restrict__ w, uint32_t* __restrict__ wp) {
    int o = blockIdx.x * 256 + threadIdx.x;
    if (o >= 512) return;
    for (int k = 0; k < 64; ++k) {
        uint32_t bits = 0;
        for (int i = 0; i < 32; ++i)
            bits |= (w[(size_t)o * 2048 + k * 32 + i] > 0.f ? 1u : 0u) << i;
        wp[k * 512 + o] = bits;
    }
}

// ---------------- conv1 mean (numpy-pairwise, h staged per 16-ch group) ----
__global__ __launch_bounds__(256) void conv1_mean(
    const float* __restrict__ x, const float* __restrict__ w1,
    float* __restrict__ mean1, int* __restrict__ zcnt) {
    __shared__ float img[1024];
    __shared__ float hbuf[16 * 784];
    __shared__ float tree[256];
    int n = blockIdx.x, tid = threadIdx.x;
    for (int i = tid; i < 1024; i += 256) img[i] = x[(size_t)n * 1024 + i];
    __syncthreads();
    int wave = tid >> 6, lane = tid & 63;
    int seg = lane >> 3, k = lane & 7;
    int soff = seg * 96 + (seg >= 4 ? 8 : 0);
    int strips = ((seg & 3) == 3) ? 13 : 12;

    for (int g = 0; g < 8; ++g) {
        for (int p = tid; p < 784; p += 256) {
            int y = p / 28, xx = p - y * 28;
            float patch[25];
#pragma unroll
            for (int ky = 0; ky < 5; ++ky)
#pragma unroll
                for (int kx = 0; kx < 5; ++kx)
                    patch[ky * 5 + kx] = img[(y + ky) * 32 + xx + kx];
#pragma unroll 2
            for (int cl = 0; cl < 16; ++cl) {
                const float* wr = w1 + (g * 16 + cl) * 25;
                hbuf[cl * 784 + p] = einsum25(patch, wr);
            }
        }
        __syncthreads();
        for (int it = 0; it < 4; ++it) {
            int cl = wave * 4 + it;
            const float* hc = &hbuf[cl * 784];
            float r = hc[soff + k];
#pragma unroll
            for (int i = 1; i < 12; ++i) r += hc[soff + 8 * i + k];
            if (strips == 13) r += hc[soff + 96 + k];
            r = r + __shfl_xor(r, 1);
            r = r + __shfl_xor(r, 2);
            r = r + __shfl_xor(r, 4);
            r = r + __shfl_xor(r, 8);
            r = r + __shfl_xor(r, 16);
            r = r + __shfl_xor(r, 32);
            if (lane == 0) tree[g * 16 + cl] = r;
        }
        __syncthreads();
    }
    int src = 0, cnt = 128;
    while (cnt > 1) {
        int dst = src + cnt;
        for (int i = tid; i < cnt / 2; i += 256) tree[dst + i] = tree[src + 2 * i] + tree[src + 2 * i + 1];
        __syncthreads();
        src = dst; cnt >>= 1;
    }
    if (tid == 0) { mean1[n] = tree[src] / 100352.0f; zcnt[n] = 0; }
}

// ---------------- conv1 binarize + pack; detect sign(0) ties ----------------
__global__ __launch_bounds__(256) void conv1_bin(
    const float* __restrict__ x, const float* __restrict__ w1,
    const float* __restrict__ mean1, uint32_t* __restrict__ b1p,
    int* __restrict__ zcnt, int* __restrict__ zlist) {
    __shared__ float img[1024];
    int n = blockIdx.x, tid = threadIdx.x;
    for (int i = tid; i < 1024; i += 256) img[i] = x[(size_t)n * 1024 + i];
    __syncthreads();
    float mean = mean1[n];
    for (int p = tid; p < 784; p += 256) {
        int y = p / 28, xx = p - y * 28;
        float patch[25];
#pragma unroll
        for (int ky = 0; ky < 5; ++ky)
#pragma unroll
            for (int kx = 0; kx < 5; ++kx)
                patch[ky * 5 + kx] = img[(y + ky) * 32 + xx + kx];
        uint32_t words[4] = {0u, 0u, 0u, 0u};
#pragma unroll 2
        for (int c = 0; c < 128; ++c) {
            float h = einsum25(patch, w1 + c * 25);
            if (h > mean) words[c >> 5] |= 1u << (c & 31);
            else if (h == mean) {
                int kz = atomicAdd(&zcnt[n], 1);
                if (kz < MAXZ) zlist[n * MAXZ + kz] = p * 128 + c;
            }
        }
#pragma unroll
        for (int k = 0; k < 4; ++k) b1p[((size_t)n * 784 + p) * 4 + k] = words[k];
    }
}

// ---------------- bconv2: 28x28 -> 5x5 conv -> pool -> 12x12, tap-major ----
// weights in LDS; thread=(oc,s); block q covers 3 output rows; per thread:
// 3 py x 2 chunks of 3 px; per chunk: 12 acc chains, 10-col register window.
__global__ __launch_bounds__(256) void bconv2_kernel(
    const uint32_t* __restrict__ actg, const uint32_t* __restrict__ wp,
    uint16_t* __restrict__ rout, const int* __restrict__ zcnt,
    const int* __restrict__ zlist) {
    __shared__ __align__(16) uint32_t act[28 * 28 * 4];
    __shared__ __align__(16) uint32_t wsh[25 * 128 * 4];
    int blk = blockIdx.x;
    int n = blk >> 2, q = blk & 3;
    int tid = threadIdx.x;
    const uint32_t* src = actg + (size_t)n * 3136;
    for (int i = tid; i < 3136; i += 256) act[i] = src[i];
    for (int i = tid; i < 12800; i += 256) wsh[i] = wp[i];
    int oc = tid & 127, s = tid >> 7;
    int nz = zcnt[n]; nz = nz > MAXZ ? MAXZ : nz;
    int zy[MAXZ], zx[MAXZ], zc[MAXZ];
    for (int i = 0; i < nz; ++i) {
        int e = zlist[n * MAXZ + i];
        int p = e >> 7; zc[i] = e & 127; zy[i] = p / 28; zx[i] = p - zy[i] * 28;
    }
    __syncthreads();
    for (int py = q * 3; py < q * 3 + 3; ++py) {
        int cy = py * 2;
#pragma unroll
        for (int ch = 0; ch < 2; ++ch) {
            int pxc = s * 6 + ch * 3;
            int cx0 = pxc * 2;
            int a[2][2][3];
#pragma unroll
            for (int dy = 0; dy < 2; ++dy)
#pragma unroll
                for (int dx = 0; dx < 2; ++dx)
#pragma unroll
                    for (int j = 0; j < 3; ++j) a[dy][dx][j] = 0;
#pragma unroll
            for (int rr = 0; rr < 6; ++rr) {
                const uint32_t* rbase = &act[((cy + rr) * 28 + cx0) * 4];
                uint4 rb[10];
#pragma unroll
                for (int j = 0; j < 10; ++j) rb[j] = *(const uint4*)(rbase + j * 4);
                // dy = 0: ky = rr (valid rr<=4)
                if (rr <= 4) {
#pragma unroll
                    for (int kx = 0; kx < 5; ++kx) {
                        uint4 wv = *(const uint4*)&wsh[((rr * 5 + kx) * 128 + oc) * 4];
#pragma unroll
                        for (int j = 0; j < 3; ++j) {
                            xp4(a[0][0][j], rb[2 * j + kx], wv);
                            xp4(a[0][1][j], rb[2 * j + kx + 1], wv);
                        }
                    }
                }
                // dy = 1: ky = rr-1 (valid rr>=1)
                if (rr >= 1) {
#pragma unroll
                    for (int kx = 0; kx < 5; ++kx) {
                        uint4 wv = *(const uint4*)&wsh[(((rr - 1) * 5 + kx) * 128 + oc) * 4];
#pragma unroll
                        for (int j = 0; j < 3; ++j) {
                            xp4(a[1][0][j], rb[2 * j + kx], wv);
                            xp4(a[1][1][j], rb[2 * j + kx + 1], wv);
                        }
                    }
                }
            }
#pragma unroll
            for (int j = 0; j < 3; ++j) {
                int m[2][2];
#pragma unroll
                for (int dy = 0; dy < 2; ++dy)
#pragma unroll
                    for (int dx = 0; dx < 2; ++dx) m[dy][dx] = 3200 - 2 * a[dy][dx][j];
                for (int i = 0; i < nz; ++i) {
#pragma unroll
                    for (int dy = 0; dy < 2; ++dy)
#pragma unroll
                        for (int dx = 0; dx < 2; ++dx) {
                            int ky = zy[i] - (cy + dy);
                            int kx = zx[i] - (cx0 + 2 * j + dx);
                            if (ky >= 0 && ky < 5 && kx >= 0 && kx < 5) {
                                uint32_t word = wsh[((ky * 5 + kx) * 128 + oc) * 4 + (zc[i] >> 5)];
                                m[dy][dx] += ((word >> (zc[i] & 31)) & 1) ? 1 : -1;
                            }
                        }
                }
                int r = max(max(m[0][0], m[0][1]), max(m[1][0], m[1][1]));
                r = r > 0 ? r : 0;
                rout[((size_t)n * 144 + py * 12 + pxc + j) * 128 + oc] = (uint16_t)r;
            }
        }
    }
}

// ---------------- bconv3: 12x12 -> 3x3 conv -> 10x10 ----------------
__global__ __launch_bounds__(256) void bconv3_kernel(
    const uint32_t* __restrict__ actg, const uint32_t* __restrict__ wp,
    uint16_t* __restrict__ rout) {
    __shared__ __align__(16) uint32_t act[12 * 12 * 4];
    int blk = blockIdx.x;
    int n = blk >> 1, q = blk & 1;
    int tid = threadIdx.x;
    const uint32_t* src = actg + (size_t)n * 576;
    for (int i = tid; i < 576; i += 256) act[i] = src[i];
    int oc = tid & 127, s = tid >> 7;
    uint4 wreg[9];
#pragma unroll
    for (int t = 0; t < 9; ++t) wreg[t] = *(const uint4*)&wp[(t * 128 + oc) * 4];
    __syncthreads();
    for (int pp = q * 50 + s; pp < (q + 1) * 50; pp += 2) {
        int py = pp / 10, px = pp - py * 10;
        int acc = 0;
#pragma unroll
        for (int rr = 0; rr < 3; ++rr)
#pragma unroll
            for (int kx = 0; kx < 3; ++kx)
                xp4(acc, *(const uint4*)&act[((py + rr) * 12 + px + kx) * 4], wreg[rr * 3 + kx]);
        int r = 1152 - 2 * acc;
        r = r > 0 ? r : 0;
        rout[((size_t)n * 100 + pp) * 128 + oc] = (uint16_t)r;
    }
}

// ---------------- bconv4: 10x10 -> 3x3 conv -> pool -> 4x4 ----------------
__global__ __launch_bounds__(256) void bconv4_kernel(
    const uint32_t* __restrict__ actg, const uint32_t* __restrict__ wp,
    uint16_t* __restrict__ rout) {
    __shared__ __align__(16) uint32_t act[10 * 10 * 4];
    int n = blockIdx.x, tid = threadIdx.x;
    const uint32_t* src = actg + (size_t)n * 400;
    for (int i = tid; i < 400; i += 256) act[i] = src[i];
    int oc = tid & 127, s = tid >> 7;
    uint4 wreg[9];
#pragma unroll
    for (int t = 0; t < 9; ++t) wreg[t] = *(const uint4*)&wp[(t * 128 + oc) * 4];
    __syncthreads();
    for (int pp = s; pp < 16; pp += 2) {
        int py = pp >> 2, px = pp & 3;
        int cy = py * 2, cx = px * 2;
        int a00 = 0, a01 = 0, a10 = 0, a11 = 0;
#pragma unroll
        for (int rr = 0; rr < 4; ++rr) {
            uint4 rb[4];
#pragma unroll
            for (int j = 0; j < 4; ++j) rb[j] = *(const uint4*)&act[((cy + rr) * 10 + cx + j) * 4];
            if (rr <= 2) {
#pragma unroll
                for (int kx = 0; kx < 3; ++kx) {
                    uint4 wv = wreg[rr * 3 + kx];
                    xp4(a00, rb[kx], wv);
                    xp4(a01, rb[kx + 1], wv);
                }
            }
            if (rr >= 1) {
#pragma unroll
                for (int kx = 0; kx < 3; ++kx) {
                    uint4 wv = wreg[(rr - 1) * 3 + kx];
                    xp4(a10, rb[kx], wv);
                    xp4(a11, rb[kx + 1], wv);
                }
            }
        }
        int m00 = 1152 - 2 * a00, m01 = 1152 - 2 * a01;
        int m10 = 1152 - 2 * a10, m11 = 1152 - 2 * a11;
        int r = max(max(m00, m01), max(m10, m11));
        r = r > 0 ? r : 0;
        rout[((size_t)n * 16 + pp) * 128 + oc] = (uint16_t)r;
    }
}

// ---------------- fused numpy-pairwise mean + binarize (u16 in, LDS-staged) --
// MODE 0: NHWC word binarize (layers 2,3). MODE 1: NCHW-flatten (layer 4).
template <int NPOS, int NLEAF, int CHUNK, int L0, int L1, int MODE>
__global__ __launch_bounds__(256) void npmean_bin_kernel(
    const uint16_t* __restrict__ rbuf, const float* __restrict__ alpha,
    uint32_t* __restrict__ bp) {
    __shared__ uint32_t sh[NPOS * 64];      // NPOS*128 u16
    __shared__ float ls[2 * NLEAF];
    int n = blockIdx.x, tid = threadIdx.x;
    const int NTOT = NPOS * 128;
    const uint32_t* rb32 = (const uint32_t*)(rbuf + (size_t)n * NTOT);
    for (int i = tid; i < NPOS * 64; i += 256) sh[i] = rb32[i];
    __syncthreads();
    if (tid < NLEAF) {
        int j0 = CHUNK * (tid >> 1) + ((tid & 1) ? L0 : 0);
        int len = (tid & 1) ? L1 : L0;
        float r[8];
#pragma unroll
        for (int k = 0; k < 8; ++k) {
            int j = j0 + k;
            int c = j / NPOS, p = j - c * NPOS;
            int e = p * 128 + c;
            uint32_t w = sh[e >> 1];
            float fv = (float)((e & 1) ? (w >> 16) : (w & 0xffffu));
            r[k] = mulr(alpha[c], fv);
        }
        int i = 8;
        int lim = len - (len % 8);
        for (; i < lim; i += 8) {
#pragma unroll
            for (int k = 0; k < 8; ++k) {
                int j = j0 + i + k;
                int c = j / NPOS, p = j - c * NPOS;
                int e = p * 128 + c;
                uint32_t w = sh[e >> 1];
                float fv = (float)((e & 1) ? (w >> 16) : (w & 0xffffu));
                r[k] += mulr(alpha[c], fv);
            }
        }
        float res = ((r[0] + r[1]) + (r[2] + r[3])) + ((r[4] + r[5]) + (r[6] + r[7]));
        for (; i < len; ++i) {
            int j = j0 + i;
            int c = j / NPOS, p = j - c * NPOS;
            int e = p * 128 + c;
            uint32_t w = sh[e >> 1];
            float fv = (float)((e & 1) ? (w >> 16) : (w & 0xffffu));
            res += mulr(alpha[c], fv);
        }
        ls[tid] = res;
    }
    __syncthreads();
    int src = 0, cnt = NLEAF;
    while (cnt > 1) {
        int dst = src + cnt;
        for (int i = tid; i < cnt / 2; i += 256) ls[dst + i] = ls[src + 2 * i] + ls[src + 2 * i + 1];
        __syncthreads();
        src = dst; cnt >>= 1;
    }
    float mean = ls[src] / (float)NTOT;
    if (MODE == 0) {
        for (int widx = tid; widx < NPOS * 4; widx += 256) {
            int w = widx & 3;
            uint32_t bits = 0;
#pragma unroll
            for (int i = 0; i < 32; i += 2) {
                uint32_t pw = sh[widx * 16 + (i >> 1)];
                float v0 = mulr(alpha[w * 32 + i], (float)(pw & 0xffffu));
                float v1 = mulr(alpha[w * 32 + i + 1], (float)(pw >> 16));
                bits |= (v0 > mean ? 1u : 0u) << i;
                bits |= (v1 > mean ? 1u : 0u) << (i + 1);
            }
            bp[(size_t)n * NPOS * 4 + widx] = bits;
        }
    } else {
        if (tid < 64) {
            int w = tid;
            uint32_t bits = 0;
#pragma unroll
            for (int i = 0; i < 32; ++i) {
                int f = w * 32 + i;
                int c = f >> 4, sp = f & 15;
                int e = sp * 128 + c;
                uint32_t pw = sh[e >> 1];
                float v = mulr(alpha[c], (float)((e & 1) ? (pw >> 16) : (pw & 0xffffu)));
                bits |= (v > mean ? 1u : 0u) << i;
            }
            bp[n * 64 + w] = bits;
        }
    }
}

// ---------------- binary FC ----------------
__global__ __launch_bounds__(256) void fc_kernel(
    const uint32_t* __restrict__ bxp, const uint32_t* __restrict__ fcpT,
    const float* __restrict__ bias, const float* __restrict__ alpha,
    float* __restrict__ out) {
    __shared__ uint32_t bxs[64];
    int n = blockIdx.x, tid = threadIdx.x;
    if (tid < 64) bxs[tid] = bxp[n * 64 + tid];
    __syncthreads();
    for (int o = tid; o < 512; o += 256) {
        int acc = 0;
#pragma unroll
        for (int k = 0; k < 64; ++k) acc += __popc(bxs[k] ^ fcpT[k * 512 + o]);
        float dot = (float)(2048 - 2 * acc);
        out[(size_t)n * 512 + o] = (dot + bias[o]) * alpha[o];
    }
}

extern "C" void kernel_launch(void* const* d_in, const int* in_sizes, int n_in,
                              void* d_out, int out_size, void* d_ws, size_t ws_size,
                              hipStream_t stream) {
    const float* x   = (const float*)d_in[0];
    const float* w1  = (const float*)d_in[1];
    const float* w2  = (const float*)d_in[2];
    const float* a2  = (const float*)d_in[3];
    const float* w3  = (const float*)d_in[4];
    const float* a3  = (const float*)d_in[5];
    const float* w4  = (const float*)d_in[6];
    const float* a4  = (const float*)d_in[7];
    const float* wfc = (const float*)d_in[8];
    const float* bfc = (const float*)d_in[9];
    const float* afc = (const float*)d_in[10];
    float* out = (float*)d_out;
    char* ws = (char*)d_ws;

    uint32_t* w2p = (uint32_t*)(ws + OFF_W2P);
    uint32_t* w3p = (uint32_t*)(ws + OFF_W3P);
    uint32_t* w4p = (uint32_t*)(ws + OFF_W4P);
    uint32_t* fcp = (uint32_t*)(ws + OFF_FCP);
    float*    mean1 = (float*)(ws + OFF_STAT);
    int*      zcnt  = (int*)(ws + OFF_STAT + 8192);
    int*      zlist = (int*)(ws + OFF_STAT + 10240);
    uint32_t* b1p = (uint32_t*)(ws + OFF_B1P);
    uint16_t* h2  = (uint16_t*)(ws + OFF_H2);
    uint32_t* b2p = (uint32_t*)(ws + OFF_B2P);
    uint16_t* h3  = (uint16_t*)(ws + OFF_H3);
    uint32_t* b3p = (uint32_t*)(ws + OFF_B3P);
    uint16_t* h4  = (uint16_t*)(ws + OFF_H4);
    uint32_t* bxp = (uint32_t*)(ws + OFF_BXP);

    pack_conv_w<<<(128 * 25 + 255) / 256, 256, 0, stream>>>(w2, w2p, 25);
    pack_conv_w<<<(128 * 9 + 255) / 256, 256, 0, stream>>>(w3, w3p, 9);
    pack_conv_w<<<(128 * 9 + 255) / 256, 256, 0, stream>>>(w4, w4p, 9);
    pack_fc_w<<<2, 256, 0, stream>>>(wfc, fcp);

    conv1_mean<<<BATCH, 256, 0, stream>>>(x, w1, mean1, zcnt);
    conv1_bin<<<BATCH, 256, 0, stream>>>(x, w1, mean1, b1p, zcnt, zlist);

    bconv2_kernel<<<BATCH * 4, 256, 0, stream>>>(b1p, w2p, h2, zcnt, zlist);
    npmean_bin_kernel<144, 256, 144, 72, 72, 0><<<BATCH, 256, 0, stream>>>(h2, a2, b2p);

    bconv3_kernel<<<BATCH * 2, 256, 0, stream>>>(b2p, w3p, h3);
    npmean_bin_kernel<100, 128, 200, 96, 104, 0><<<BATCH, 256, 0, stream>>>(h3, a3, b3p);

    bconv4_kernel<<<BATCH, 256, 0, stream>>>(b3p, w4p, h4);
    npmean_bin_kernel<16, 16, 256, 128, 128, 1><<<BATCH, 256, 0, stream>>>(h4, a4, bxp);

    fc_kernel<<<BATCH, 256, 0, stream>>>(bxp, fcp, bfc, afc, out);
}

// Round 12
// 899.290 us; speedup vs baseline: 1.1032x; 1.1032x over previous
//
#include <hip/hip_runtime.h>
#include <stdint.h>

#define BATCH 512
#define MAXZ 3

// ---- workspace layout (bytes) ----
static const size_t OFF_W2P  = 0;          // 25*128*4 u32
static const size_t OFF_W3P  = 51200;
static const size_t OFF_W4P  = 69632;
static const size_t OFF_FCP  = 88064;
static const size_t OFF_STAT = 219136;     // mean1 f32[512]@0; zcnt int[512]@8192; zlist int[512*3]@10240
static const size_t OFF_B1P  = 235520;     // 512*784*16
static const size_t OFF_H2   = 6658048;    // 512*144*128*2 u16 counts (exact)
static const size_t OFF_B2P  = 44406784;
static const size_t OFF_H3   = 45586432;   // 512*100*128*2 u16
static const size_t OFF_B3P  = 71800832;
static const size_t OFF_H4   = 72620032;   // 512*16*128*2 u16
static const size_t OFF_BXP  = 76814336;
// end ~76.9 MB

// Numerics model (validated r8-r11, absmax=0): conv1 = np.einsum f32 SSE2
// order (separately-rounded mul/add); means = numpy pairwise-f32; sign(0)
// ties -> zlist fixup in conv2; binary layers exact integer xnor-popcount.
// Counts fit u16 exactly; u16->f32 conversion exact => identical decisions.

__device__ inline float mulr(float a, float b) {
    float t = a * b;
    asm volatile("" : "+v"(t));
    return t;
}

// chained xor-popcount accumulate (folds to v_bcnt_u32_b32 with acc operand)
__device__ inline void xp4(int& acc, uint4 a, uint4 b) {
    acc += __popc(a.x ^ b.x);
    acc += __popc(a.y ^ b.y);
    acc += __popc(a.z ^ b.z);
    acc += __popc(a.w ^ b.w);
}

// einsum SSE2-order 25-tap dot + relu, separately-rounded mul/add (no FMA).
__device__ inline float einsum25(const float* __restrict__ patch,
                                 const float* __restrict__ wr) {
#pragma clang fp contract(off)
    float l0 = wr[0] * patch[0];
    float l1 = wr[1] * patch[1];
    float l2 = wr[2] * patch[2];
    float l3 = wr[3] * patch[3];
#pragma unroll
    for (int t = 1; t < 6; ++t) {
        l0 += wr[4 * t + 0] * patch[4 * t + 0];
        l1 += wr[4 * t + 1] * patch[4 * t + 1];
        l2 += wr[4 * t + 2] * patch[4 * t + 2];
        l3 += wr[4 * t + 3] * patch[4 * t + 3];
    }
    float acc = (l0 + l1) + (l2 + l3);
    acc += wr[24] * patch[24];
    return acc > 0.f ? acc : 0.f;
}

// ---------------- weight packing ----------------
__global__ void pack_conv_w(const float* __restrict__ w, uint32_t* __restrict__ wp, int taps) {
    int idx = blockIdx.x * 256 + threadIdx.x;
    if (idx >= 128 * taps) return;
    int oc = idx / taps, t = idx - oc * taps;
    uint32_t words[4] = {0u, 0u, 0u, 0u};
    for (int ic = 0; ic < 128; ++ic) {
        float v = w[(size_t)(oc * 128 + ic) * taps + t];
        if (v > 0.f) words[ic >> 5] |= 1u << (ic & 31);
    }
#pragma unroll
    for (int k = 0; k < 4; ++k) wp[((size_t)t * 128 + oc) * 4 + k] = words[k];
}

__global__ void pack_fc_w(const float* __restrict__ w, uint32_t* __restrict__ wp) {
    int o = blockIdx.x * 256 + threadIdx.x;
    if (o >= 512) return;
    for (int k = 0; k < 64; ++k) {
        uint32_t bits = 0;
        for (int i = 0; i < 32; ++i)
            bits |= (w[(size_t)o * 2048 + k * 32 + i] > 0.f ? 1u : 0u) << i;
        wp[k * 512 + o] = bits;
    }
}

// ---------------- conv1 mean (numpy-pairwise, h staged per 16-ch group) ----
__global__ __launch_bounds__(256) void conv1_mean(
    const float* __restrict__ x, const float* __restrict__ w1,
    float* __restrict__ mean1, int* __restrict__ zcnt) {
    __shared__ float img[1024];
    __shared__ float hbuf[16 * 784];
    __shared__ float tree[256];
    int n = blockIdx.x, tid = threadIdx.x;
    for (int i = tid; i < 1024; i += 256) img[i] = x[(size_t)n * 1024 + i];
    __syncthreads();
    int wave = tid >> 6, lane = tid & 63;
    int seg = lane >> 3, k = lane & 7;
    int soff = seg * 96 + (seg >= 4 ? 8 : 0);
    int strips = ((seg & 3) == 3) ? 13 : 12;

    for (int g = 0; g < 8; ++g) {
        for (int p = tid; p < 784; p += 256) {
            int y = p / 28, xx = p - y * 28;
            float patch[25];
#pragma unroll
            for (int ky = 0; ky < 5; ++ky)
#pragma unroll
                for (int kx = 0; kx < 5; ++kx)
                    patch[ky * 5 + kx] = img[(y + ky) * 32 + xx + kx];
#pragma unroll 2
            for (int cl = 0; cl < 16; ++cl) {
                const float* wr = w1 + (g * 16 + cl) * 25;
                hbuf[cl * 784 + p] = einsum25(patch, wr);
            }
        }
        __syncthreads();
        for (int it = 0; it < 4; ++it) {
            int cl = wave * 4 + it;
            const float* hc = &hbuf[cl * 784];
            float r = hc[soff + k];
#pragma unroll
            for (int i = 1; i < 12; ++i) r += hc[soff + 8 * i + k];
            if (strips == 13) r += hc[soff + 96 + k];
            r = r + __shfl_xor(r, 1);
            r = r + __shfl_xor(r, 2);
            r = r + __shfl_xor(r, 4);
            r = r + __shfl_xor(r, 8);
            r = r + __shfl_xor(r, 16);
            r = r + __shfl_xor(r, 32);
            if (lane == 0) tree[g * 16 + cl] = r;
        }
        __syncthreads();
    }
    int src = 0, cnt = 128;
    while (cnt > 1) {
        int dst = src + cnt;
        for (int i = tid; i < cnt / 2; i += 256) tree[dst + i] = tree[src + 2 * i] + tree[src + 2 * i + 1];
        __syncthreads();
        src = dst; cnt >>= 1;
    }
    if (tid == 0) { mean1[n] = tree[src] / 100352.0f; zcnt[n] = 0; }
}

// ---------------- conv1 binarize + pack; detect sign(0) ties ----------------
__global__ __launch_bounds__(256) void conv1_bin(
    const float* __restrict__ x, const float* __restrict__ w1,
    const float* __restrict__ mean1, uint32_t* __restrict__ b1p,
    int* __restrict__ zcnt, int* __restrict__ zlist) {
    __shared__ float img[1024];
    int n = blockIdx.x, tid = threadIdx.x;
    for (int i = tid; i < 1024; i += 256) img[i] = x[(size_t)n * 1024 + i];
    __syncthreads();
    float mean = mean1[n];
    for (int p = tid; p < 784; p += 256) {
        int y = p / 28, xx = p - y * 28;
        float patch[25];
#pragma unroll
        for (int ky = 0; ky < 5; ++ky)
#pragma unroll
            for (int kx = 0; kx < 5; ++kx)
                patch[ky * 5 + kx] = img[(y + ky) * 32 + xx + kx];
        uint32_t words[4] = {0u, 0u, 0u, 0u};
#pragma unroll 2
        for (int c = 0; c < 128; ++c) {
            float h = einsum25(patch, w1 + c * 25);
            if (h > mean) words[c >> 5] |= 1u << (c & 31);
            else if (h == mean) {
                int kz = atomicAdd(&zcnt[n], 1);
                if (kz < MAXZ) zlist[n * MAXZ + kz] = p * 128 + c;
            }
        }
#pragma unroll
        for (int k = 0; k < 4; ++k) b1p[((size_t)n * 784 + p) * 4 + k] = words[k];
    }
}

// ---------------- bconv2: 28x28 -> 5x5 conv -> pool -> 12x12, half-split ----
// Each oc's 128-bit popcount is split over 2 lanes (2 u32 words each):
// weights = 25 x uint2 in VGPRs (50 regs); act reads = b64 broadcast pairs;
// halves combine with one shfl_xor per subposition. LDS = act only (12.5KB).
__global__ __launch_bounds__(256) void bconv2_kernel(
    const uint32_t* __restrict__ actg, const uint32_t* __restrict__ wp,
    uint16_t* __restrict__ rout, const int* __restrict__ zcnt,
    const int* __restrict__ zlist) {
    __shared__ __align__(16) uint32_t act[28 * 28 * 4];
    int blk = blockIdx.x;
    int n = blk >> 2, q = blk & 3;
    int tid = threadIdx.x;
    const uint32_t* src = actg + (size_t)n * 3136;
    for (int i = tid; i < 3136; i += 256) act[i] = src[i];
    int lane = tid & 63, wid = tid >> 6;
    int half = lane & 1;
    int oc = wid * 32 + (lane >> 1);
    uint2 w[25];
#pragma unroll
    for (int t = 0; t < 25; ++t)
        w[t] = *(const uint2*)&wp[(t * 128 + oc) * 4 + half * 2];
    int nz = zcnt[n]; nz = nz > MAXZ ? MAXZ : nz;
    int zy[MAXZ], zx[MAXZ], zc[MAXZ];
    for (int i = 0; i < nz; ++i) {
        int e = zlist[n * MAXZ + i];
        int p = e >> 7; zc[i] = e & 127; zy[i] = p / 28; zx[i] = p - zy[i] * 28;
    }
    __syncthreads();
    for (int pp = q * 36; pp < q * 36 + 36; ++pp) {
        int py = pp / 12, px = pp - py * 12;
        int cy = py * 2, cx = px * 2;
        int a00 = 0, a01 = 0, a10 = 0, a11 = 0;
#pragma unroll
        for (int rr = 0; rr < 6; ++rr) {
            uint2 rb[6];
#pragma unroll
            for (int j = 0; j < 6; ++j)
                rb[j] = *(const uint2*)&act[((cy + rr) * 28 + cx + j) * 4 + half * 2];
            if (rr <= 4) {
#pragma unroll
                for (int kx = 0; kx < 5; ++kx) {
                    uint2 wv = w[rr * 5 + kx];
                    a00 += __popc(rb[kx].x ^ wv.x);     a00 += __popc(rb[kx].y ^ wv.y);
                    a01 += __popc(rb[kx + 1].x ^ wv.x); a01 += __popc(rb[kx + 1].y ^ wv.y);
                }
            }
            if (rr >= 1) {
#pragma unroll
                for (int kx = 0; kx < 5; ++kx) {
                    uint2 wv = w[(rr - 1) * 5 + kx];
                    a10 += __popc(rb[kx].x ^ wv.x);     a10 += __popc(rb[kx].y ^ wv.y);
                    a11 += __popc(rb[kx + 1].x ^ wv.x); a11 += __popc(rb[kx + 1].y ^ wv.y);
                }
            }
        }
        int t00 = 2 * a00, t01 = 2 * a01, t10 = 2 * a10, t11 = 2 * a11;
        if (nz) {
            // remove spurious (-1)-act contribution for tie channels this half owns
            for (int i = 0; i < nz; ++i) {
                int wordidx = zc[i] >> 5;
                if ((wordidx >> 1) != half) continue;
                int wsub = wordidx & 1, bit = zc[i] & 31;
#pragma unroll
                for (int d = 0; d < 4; ++d) {
                    int ky = zy[i] - (cy + (d >> 1)), kx = zx[i] - (cx + (d & 1));
                    if (ky >= 0 && ky < 5 && kx >= 0 && kx < 5) {
                        uint2 wv = w[ky * 5 + kx];
                        uint32_t word = wsub ? wv.y : wv.x;
                        int adj = ((word >> bit) & 1) ? 1 : -1;   // m += adj  <=>  t -= adj
                        if (d == 0) t00 -= adj; else if (d == 1) t01 -= adj;
                        else if (d == 2) t10 -= adj; else t11 -= adj;
                    }
                }
            }
        }
        t00 += __shfl_xor(t00, 1); t01 += __shfl_xor(t01, 1);
        t10 += __shfl_xor(t10, 1); t11 += __shfl_xor(t11, 1);
        int m = max(max(3200 - t00, 3200 - t01), max(3200 - t10, 3200 - t11));
        m = m > 0 ? m : 0;
        if (half == 0)
            rout[((size_t)n * 144 + pp) * 128 + oc] = (uint16_t)m;
    }
}

// ---------------- bconv3: 12x12 -> 3x3 conv -> 10x10 ----------------
__global__ __launch_bounds__(256) void bconv3_kernel(
    const uint32_t* __restrict__ actg, const uint32_t* __restrict__ wp,
    uint16_t* __restrict__ rout) {
    __shared__ __align__(16) uint32_t act[12 * 12 * 4];
    int blk = blockIdx.x;
    int n = blk >> 1, q = blk & 1;
    int tid = threadIdx.x;
    const uint32_t* src = actg + (size_t)n * 576;
    for (int i = tid; i < 576; i += 256) act[i] = src[i];
    int oc = tid & 127, s = tid >> 7;
    uint4 wreg[9];
#pragma unroll
    for (int t = 0; t < 9; ++t) wreg[t] = *(const uint4*)&wp[(t * 128 + oc) * 4];
    __syncthreads();
    for (int pp = q * 50 + s; pp < (q + 1) * 50; pp += 2) {
        int py = pp / 10, px = pp - py * 10;
        int acc = 0;
#pragma unroll
        for (int rr = 0; rr < 3; ++rr)
#pragma unroll
            for (int kx = 0; kx < 3; ++kx)
                xp4(acc, *(const uint4*)&act[((py + rr) * 12 + px + kx) * 4], wreg[rr * 3 + kx]);
        int r = 1152 - 2 * acc;
        r = r > 0 ? r : 0;
        rout[((size_t)n * 100 + pp) * 128 + oc] = (uint16_t)r;
    }
}

// ---------------- bconv4: 10x10 -> 3x3 conv -> pool -> 4x4 ----------------
__global__ __launch_bounds__(256) void bconv4_kernel(
    const uint32_t* __restrict__ actg, const uint32_t* __restrict__ wp,
    uint16_t* __restrict__ rout) {
    __shared__ __align__(16) uint32_t act[10 * 10 * 4];
    int n = blockIdx.x, tid = threadIdx.x;
    const uint32_t* src = actg + (size_t)n * 400;
    for (int i = tid; i < 400; i += 256) act[i] = src[i];
    int oc = tid & 127, s = tid >> 7;
    uint4 wreg[9];
#pragma unroll
    for (int t = 0; t < 9; ++t) wreg[t] = *(const uint4*)&wp[(t * 128 + oc) * 4];
    __syncthreads();
    for (int pp = s; pp < 16; pp += 2) {
        int py = pp >> 2, px = pp & 3;
        int cy = py * 2, cx = px * 2;
        int a00 = 0, a01 = 0, a10 = 0, a11 = 0;
#pragma unroll
        for (int rr = 0; rr < 4; ++rr) {
            uint4 rb[4];
#pragma unroll
            for (int j = 0; j < 4; ++j) rb[j] = *(const uint4*)&act[((cy + rr) * 10 + cx + j) * 4];
            if (rr <= 2) {
#pragma unroll
                for (int kx = 0; kx < 3; ++kx) {
                    uint4 wv = wreg[rr * 3 + kx];
                    xp4(a00, rb[kx], wv);
                    xp4(a01, rb[kx + 1], wv);
                }
            }
            if (rr >= 1) {
#pragma unroll
                for (int kx = 0; kx < 3; ++kx) {
                    uint4 wv = wreg[(rr - 1) * 3 + kx];
                    xp4(a10, rb[kx], wv);
                    xp4(a11, rb[kx + 1], wv);
                }
            }
        }
        int m00 = 1152 - 2 * a00, m01 = 1152 - 2 * a01;
        int m10 = 1152 - 2 * a10, m11 = 1152 - 2 * a11;
        int r = max(max(m00, m01), max(m10, m11));
        r = r > 0 ? r : 0;
        rout[((size_t)n * 16 + pp) * 128 + oc] = (uint16_t)r;
    }
}

// ---------------- fused numpy-pairwise mean + binarize (u16 in, LDS-staged) --
// MODE 0: NHWC word binarize (layers 2,3). MODE 1: NCHW-flatten (layer 4).
template <int NPOS, int NLEAF, int CHUNK, int L0, int L1, int MODE>
__global__ __launch_bounds__(256) void npmean_bin_kernel(
    const uint16_t* __restrict__ rbuf, const float* __restrict__ alpha,
    uint32_t* __restrict__ bp) {
    __shared__ uint32_t sh[NPOS * 64];      // NPOS*128 u16
    __shared__ float ls[2 * NLEAF];
    int n = blockIdx.x, tid = threadIdx.x;
    const int NTOT = NPOS * 128;
    const uint32_t* rb32 = (const uint32_t*)(rbuf + (size_t)n * NTOT);
    for (int i = tid; i < NPOS * 64; i += 256) sh[i] = rb32[i];
    __syncthreads();
    if (tid < NLEAF) {
        int j0 = CHUNK * (tid >> 1) + ((tid & 1) ? L0 : 0);
        int len = (tid & 1) ? L1 : L0;
        float r[8];
#pragma unroll
        for (int k = 0; k < 8; ++k) {
            int j = j0 + k;
            int c = j / NPOS, p = j - c * NPOS;
            int e = p * 128 + c;
            uint32_t w = sh[e >> 1];
            float fv = (float)((e & 1) ? (w >> 16) : (w & 0xffffu));
            r[k] = mulr(alpha[c], fv);
        }
        int i = 8;
        int lim = len - (len % 8);
        for (; i < lim; i += 8) {
#pragma unroll
            for (int k = 0; k < 8; ++k) {
                int j = j0 + i + k;
                int c = j / NPOS, p = j - c * NPOS;
                int e = p * 128 + c;
                uint32_t w = sh[e >> 1];
                float fv = (float)((e & 1) ? (w >> 16) : (w & 0xffffu));
                r[k] += mulr(alpha[c], fv);
            }
        }
        float res = ((r[0] + r[1]) + (r[2] + r[3])) + ((r[4] + r[5]) + (r[6] + r[7]));
        for (; i < len; ++i) {
            int j = j0 + i;
            int c = j / NPOS, p = j - c * NPOS;
            int e = p * 128 + c;
            uint32_t w = sh[e >> 1];
            float fv = (float)((e & 1) ? (w >> 16) : (w & 0xffffu));
            res += mulr(alpha[c], fv);
        }
        ls[tid] = res;
    }
    __syncthreads();
    int src = 0, cnt = NLEAF;
    while (cnt > 1) {
        int dst = src + cnt;
        for (int i = tid; i < cnt / 2; i += 256) ls[dst + i] = ls[src + 2 * i] + ls[src + 2 * i + 1];
        __syncthreads();
        src = dst; cnt >>= 1;
    }
    float mean = ls[src] / (float)NTOT;
    if (MODE == 0) {
        for (int widx = tid; widx < NPOS * 4; widx += 256) {
            int w = widx & 3;
            uint32_t bits = 0;
#pragma unroll
            for (int i = 0; i < 32; i += 2) {
                uint32_t pw = sh[widx * 16 + (i >> 1)];
                float v0 = mulr(alpha[w * 32 + i], (float)(pw & 0xffffu));
                float v1 = mulr(alpha[w * 32 + i + 1], (float)(pw >> 16));
                bits |= (v0 > mean ? 1u : 0u) << i;
                bits |= (v1 > mean ? 1u : 0u) << (i + 1);
            }
            bp[(size_t)n * NPOS * 4 + widx] = bits;
        }
    } else {
        if (tid < 64) {
            int w = tid;
            uint32_t bits = 0;
#pragma unroll
            for (int i = 0; i < 32; ++i) {
                int f = w * 32 + i;
                int c = f >> 4, sp = f & 15;
                int e = sp * 128 + c;
                uint32_t pw = sh[e >> 1];
                float v = mulr(alpha[c], (float)((e & 1) ? (pw >> 16) : (pw & 0xffffu)));
                bits |= (v > mean ? 1u : 0u) << i;
            }
            bp[n * 64 + w] = bits;
        }
    }
}

// ---------------- binary FC ----------------
__global__ __launch_bounds__(256) void fc_kernel(
    const uint32_t* __restrict__ bxp, const uint32_t* __restrict__ fcpT,
    const float* __restrict__ bias, const float* __restrict__ alpha,
    float* __restrict__ out) {
    __shared__ uint32_t bxs[64];
    int n = blockIdx.x, tid = threadIdx.x;
    if (tid < 64) bxs[tid] = bxp[n * 64 + tid];
    __syncthreads();
    for (int o = tid; o < 512; o += 256) {
        int acc = 0;
#pragma unroll
        for (int k = 0; k < 64; ++k) acc += __popc(bxs[k] ^ fcpT[k * 512 + o]);
        float dot = (float)(2048 - 2 * acc);
        out[(size_t)n * 512 + o] = (dot + bias[o]) * alpha[o];
    }
}

extern "C" void kernel_launch(void* const* d_in, const int* in_sizes, int n_in,
                              void* d_out, int out_size, void* d_ws, size_t ws_size,
                              hipStream_t stream) {
    const float* x   = (const float*)d_in[0];
    const float* w1  = (const float*)d_in[1];
    const float* w2  = (const float*)d_in[2];
    const float* a2  = (const float*)d_in[3];
    const float* w3  = (const float*)d_in[4];
    const float* a3  = (const float*)d_in[5];
    const float* w4  = (const float*)d_in[6];
    const float* a4  = (const float*)d_in[7];
    const float* wfc = (const float*)d_in[8];
    const float* bfc = (const float*)d_in[9];
    const float* afc = (const float*)d_in[10];
    float* out = (float*)d_out;
    char* ws = (char*)d_ws;

    uint32_t* w2p = (uint32_t*)(ws + OFF_W2P);
    uint32_t* w3p = (uint32_t*)(ws + OFF_W3P);
    uint32_t* w4p = (uint32_t*)(ws + OFF_W4P);
    uint32_t* fcp = (uint32_t*)(ws + OFF_FCP);
    float*    mean1 = (float*)(ws + OFF_STAT);
    int*      zcnt  = (int*)(ws + OFF_STAT + 8192);
    int*      zlist = (int*)(ws + OFF_STAT + 10240);
    uint32_t* b1p = (uint32_t*)(ws + OFF_B1P);
    uint16_t* h2  = (uint16_t*)(ws + OFF_H2);
    uint32_t* b2p = (uint32_t*)(ws + OFF_B2P);
    uint16_t* h3  = (uint16_t*)(ws + OFF_H3);
    uint32_t* b3p = (uint32_t*)(ws + OFF_B3P);
    uint16_t* h4  = (uint16_t*)(ws + OFF_H4);
    uint32_t* bxp = (uint32_t*)(ws + OFF_BXP);

    pack_conv_w<<<(128 * 25 + 255) / 256, 256, 0, stream>>>(w2, w2p, 25);
    pack_conv_w<<<(128 * 9 + 255) / 256, 256, 0, stream>>>(w3, w3p, 9);
    pack_conv_w<<<(128 * 9 + 255) / 256, 256, 0, stream>>>(w4, w4p, 9);
    pack_fc_w<<<2, 256, 0, stream>>>(wfc, fcp);

    conv1_mean<<<BATCH, 256, 0, stream>>>(x, w1, mean1, zcnt);
    conv1_bin<<<BATCH, 256, 0, stream>>>(x, w1, mean1, b1p, zcnt, zlist);

    bconv2_kernel<<<BATCH * 4, 256, 0, stream>>>(b1p, w2p, h2, zcnt, zlist);
    npmean_bin_kernel<144, 256, 144, 72, 72, 0><<<BATCH, 256, 0, stream>>>(h2, a2, b2p);

    bconv3_kernel<<<BATCH * 2, 256, 0, stream>>>(b2p, w3p, h3);
    npmean_bin_kernel<100, 128, 200, 96, 104, 0><<<BATCH, 256, 0, stream>>>(h3, a3, b3p);

    bconv4_kernel<<<BATCH, 256, 0, stream>>>(b3p, w4p, h4);
    npmean_bin_kernel<16, 16, 256, 128, 128, 1><<<BATCH, 256, 0, stream>>>(h4, a4, bxp);

    fc_kernel<<<BATCH, 256, 0, stream>>>(bxp, fcp, bfc, afc, out);
}

// Round 13
// 699.509 us; speedup vs baseline: 1.4183x; 1.2856x over previous
//
#include <hip/hip_runtime.h>
#include <stdint.h>

#define BATCH 512
#define MAXZ 3

typedef int v4i __attribute__((ext_vector_type(4)));

// ---- workspace layout (bytes) ----
static const size_t OFF_W2F  = 0;          // 50*8*64*16 i8 B-frags = 409600
static const size_t OFF_W3P  = 409600;     // 9*128*4 u32
static const size_t OFF_W4P  = 428032;
static const size_t OFF_FCP  = 446464;     // 64*512 u32
static const size_t OFF_STAT = 577536;     // mean1 f32[512]@0; zcnt@8192; zlist@10240
static const size_t OFF_B1P  = 593920;     // 512*784*16
static const size_t OFF_H2   = 7016448;    // 512*144*128*2 u16
static const size_t OFF_B2P  = 25890816;   // 512*144*16
static const size_t OFF_H3   = 27070464;   // 512*100*128*2 u16
static const size_t OFF_B3P  = 40177664;   // 512*100*16
static const size_t OFF_H4   = 40996864;   // 512*16*128*2 u16
static const size_t OFF_BXP  = 43094016;   // 512*64*4
// end ~43.2 MB

// Numerics model (validated r8-r12, absmax=0): conv1 = np.einsum f32 SSE2
// order; means = numpy pairwise-f32; binary layers exact integer math.
// NEW r13: conv2 as i8 MFMA GEMM — act i8 in {-1,0,+1} (0 = sign-tie,
// poked during staging; replaces the zlist popcount fixup), w i8 in {-1,+1};
// i32 accumulate is exact. Fragment layouts per cdna4 guide (m89-verified
// C: col=lane&15,row=(lane>>4)*4+reg; A: m=lane&15,k=(lane>>4)*16+j; B
// mirrored). Pool(relu(alpha*m)) == alpha*relu(max m) since alpha>0.

__device__ inline float mulr(float a, float b) {
    float t = a * b;
    asm volatile("" : "+v"(t));
    return t;
}

__device__ inline void xp4(int& acc, uint4 a, uint4 b) {
    acc += __popc(a.x ^ b.x);
    acc += __popc(a.y ^ b.y);
    acc += __popc(a.z ^ b.z);
    acc += __popc(a.w ^ b.w);
}

__device__ inline float einsum25(const float* __restrict__ patch,
                                 const float* __restrict__ wr) {
#pragma clang fp contract(off)
    float l0 = wr[0] * patch[0];
    float l1 = wr[1] * patch[1];
    float l2 = wr[2] * patch[2];
    float l3 = wr[3] * patch[3];
#pragma unroll
    for (int t = 1; t < 6; ++t) {
        l0 += wr[4 * t + 0] * patch[4 * t + 0];
        l1 += wr[4 * t + 1] * patch[4 * t + 1];
        l2 += wr[4 * t + 2] * patch[4 * t + 2];
        l3 += wr[4 * t + 3] * patch[4 * t + 3];
    }
    float acc = (l0 + l1) + (l2 + l3);
    acc += wr[24] * patch[24];
    return acc > 0.f ? acc : 0.f;
}

// ---------------- weight packing ----------------
__global__ void pack_conv_w(const float* __restrict__ w, uint32_t* __restrict__ wp, int taps) {
    int idx = blockIdx.x * 256 + threadIdx.x;
    if (idx >= 128 * taps) return;
    int oc = idx / taps, t = idx - oc * taps;
    uint32_t words[4] = {0u, 0u, 0u, 0u};
    for (int ic = 0; ic < 128; ++ic) {
        float v = w[(size_t)(oc * 128 + ic) * taps + t];
        if (v > 0.f) words[ic >> 5] |= 1u << (ic & 31);
    }
#pragma unroll
    for (int k = 0; k < 4; ++k) wp[((size_t)t * 128 + oc) * 4 + k] = words[k];
}

// w2 -> i8 B-fragment order [kstep(50)][octile(8)][lane(64)][16 i8]
// entry: oc = octile*16 + (lane&15); k = kstep*64 + (lane>>4)*16 + j;
// tap = k>>7; ch = k&127; val = w2[oc][ch][tap] > 0 ? +1 : -1
__global__ void pack_w2_frag(const float* __restrict__ w2, uint32_t* __restrict__ b2f) {
    int d = blockIdx.x * 256 + threadIdx.x;   // dword index, total 102400
    if (d >= 102400) return;
    int j4 = d & 3;
    int lane = (d >> 2) & 63;
    int ok = d >> 8;
    int octile = ok & 7, kstep = ok >> 3;
    int oc = octile * 16 + (lane & 15);
    uint32_t dv = 0;
#pragma unroll
    for (int jj = 0; jj < 4; ++jj) {
        int j = j4 * 4 + jj;
        int k = kstep * 64 + (lane >> 4) * 16 + j;
        int tap = k >> 7, ch = k & 127;
        uint32_t byte = (w2[(size_t)(oc * 128 + ch) * 25 + tap] > 0.f) ? 0x01u : 0xFFu;
        dv |= byte << (8 * jj);
    }
    b2f[d] = dv;
}

__global__ void pack_fc_w(const float* __restrict__ w, uint32_t* __restrict__ wp) {
    int o = blockIdx.x * 256 + threadIdx.x;
    if (o >= 512) return;
    for (int k = 0; k < 64; ++k) {
        uint32_t bits = 0;
        for (int i = 0; i < 32; ++i)
            bits |= (w[(size_t)o * 2048 + k * 32 + i] > 0.f ? 1u : 0u) << i;
        wp[k * 512 + o] = bits;
    }
}

// ---------------- conv1 mean (numpy-pairwise, h staged per 16-ch group) ----
__global__ __launch_bounds__(256) void conv1_mean(
    const float* __restrict__ x, const float* __restrict__ w1,
    float* __restrict__ mean1, int* __restrict__ zcnt) {
    __shared__ float img[1024];
    __shared__ float hbuf[16 * 784];
    __shared__ float tree[256];
    int n = blockIdx.x, tid = threadIdx.x;
    for (int i = tid; i < 1024; i += 256) img[i] = x[(size_t)n * 1024 + i];
    __syncthreads();
    int wave = tid >> 6, lane = tid & 63;
    int seg = lane >> 3, k = lane & 7;
    int soff = seg * 96 + (seg >= 4 ? 8 : 0);
    int strips = ((seg & 3) == 3) ? 13 : 12;

    for (int g = 0; g < 8; ++g) {
        for (int p = tid; p < 784; p += 256) {
            int y = p / 28, xx = p - y * 28;
            float patch[25];
#pragma unroll
            for (int ky = 0; ky < 5; ++ky)
#pragma unroll
                for (int kx = 0; kx < 5; ++kx)
                    patch[ky * 5 + kx] = img[(y + ky) * 32 + xx + kx];
#pragma unroll 2
            for (int cl = 0; cl < 16; ++cl) {
                const float* wr = w1 + (g * 16 + cl) * 25;
                hbuf[cl * 784 + p] = einsum25(patch, wr);
            }
        }
        __syncthreads();
        for (int it = 0; it < 4; ++it) {
            int cl = wave * 4 + it;
            const float* hc = &hbuf[cl * 784];
            float r = hc[soff + k];
#pragma unroll
            for (int i = 1; i < 12; ++i) r += hc[soff + 8 * i + k];
            if (strips == 13) r += hc[soff + 96 + k];
            r = r + __shfl_xor(r, 1);
            r = r + __shfl_xor(r, 2);
            r = r + __shfl_xor(r, 4);
            r = r + __shfl_xor(r, 8);
            r = r + __shfl_xor(r, 16);
            r = r + __shfl_xor(r, 32);
            if (lane == 0) tree[g * 16 + cl] = r;
        }
        __syncthreads();
    }
    int src = 0, cnt = 128;
    while (cnt > 1) {
        int dst = src + cnt;
        for (int i = tid; i < cnt / 2; i += 256) tree[dst + i] = tree[src + 2 * i] + tree[src + 2 * i + 1];
        __syncthreads();
        src = dst; cnt >>= 1;
    }
    if (tid == 0) { mean1[n] = tree[src] / 100352.0f; zcnt[n] = 0; }
}

// ---------------- conv1 binarize + pack; detect sign(0) ties ----------------
__global__ __launch_bounds__(256) void conv1_bin(
    const float* __restrict__ x, const float* __restrict__ w1,
    const float* __restrict__ mean1, uint32_t* __restrict__ b1p,
    int* __restrict__ zcnt, int* __restrict__ zlist) {
    __shared__ float img[1024];
    int n = blockIdx.x, tid = threadIdx.x;
    for (int i = tid; i < 1024; i += 256) img[i] = x[(size_t)n * 1024 + i];
    __syncthreads();
    float mean = mean1[n];
    for (int p = tid; p < 784; p += 256) {
        int y = p / 28, xx = p - y * 28;
        float patch[25];
#pragma unroll
        for (int ky = 0; ky < 5; ++ky)
#pragma unroll
            for (int kx = 0; kx < 5; ++kx)
                patch[ky * 5 + kx] = img[(y + ky) * 32 + xx + kx];
        uint32_t words[4] = {0u, 0u, 0u, 0u};
#pragma unroll 2
        for (int c = 0; c < 128; ++c) {
            float h = einsum25(patch, w1 + c * 25);
            if (h > mean) words[c >> 5] |= 1u << (c & 31);
            else if (h == mean) {
                int kz = atomicAdd(&zcnt[n], 1);
                if (kz < MAXZ) zlist[n * MAXZ + kz] = p * 128 + c;
            }
        }
#pragma unroll
        for (int k = 0; k < 4; ++k) b1p[((size_t)n * 784 + p) * 4 + k] = words[k];
    }
}

// ---------------- bconv2 via i8 MFMA ----------------
// block = (n, pooled row r). 2 waves x 128 thr. LDS: act i8 rows 2r..2r+5.
// wave w: oc-tiles 4w..4w+3; 3 pos-tiles of 16 positions ordered
// pos_local = pair*4 + dy*2 + dx (pair = pooled col within tile).
__global__ __launch_bounds__(128) void bconv2_mfma(
    const uint32_t* __restrict__ b1p, const uint8_t* __restrict__ b2f,
    uint16_t* __restrict__ rout, const int* __restrict__ zcnt,
    const int* __restrict__ zlist) {
    __shared__ __align__(16) uint32_t acts32[5376];   // 6*28*128 i8
    uint8_t* acts = (uint8_t*)acts32;
    int blk = blockIdx.x;
    int n = blk / 12, r = blk - n * 12;
    int tid = threadIdx.x;
    // stage: expand bits -> i8 (+1/-1)
    const uint32_t* bsrc = b1p + ((size_t)n * 784 + 2 * r * 28) * 4;
    for (int d = tid; d < 5376; d += 128) {
        int pos = d >> 5;            // 0..167 (ry*28+x)
        int nibidx = d & 31;
        uint32_t word = bsrc[pos * 4 + (nibidx >> 3)];
        uint32_t nib = (word >> ((nibidx & 7) * 4)) & 0xF;
        uint32_t spread = (nib * 0x00204081u) & 0x01010101u;
        acts32[d] = ~(spread * 0xFEu);   // bit->+1 (0x01), clear->-1 (0xFF)
    }
    __syncthreads();
    if (tid == 0) {
        int nz = zcnt[n]; nz = nz > MAXZ ? MAXZ : nz;
        for (int i = 0; i < nz; ++i) {
            int e = zlist[n * MAXZ + i];
            int p = e >> 7, zc = e & 127;
            int zy = p / 28, zx = p - zy * 28;
            int ry = zy - 2 * r;
            if (ry >= 0 && ry < 6) acts[(ry * 28 + zx) * 128 + zc] = 0;  // sign(0)
        }
    }
    __syncthreads();

    int lane = tid & 63, w = tid >> 6;
    int ml = lane & 15, khi = lane >> 4;
    int pairl = ml >> 2, dy = (ml >> 1) & 1, dx = ml & 1;
    int abase[3];
#pragma unroll
    for (int t = 0; t < 3; ++t) {
        int px = 2 * (4 * t + pairl) + dx;
        abase[t] = (dy * 28 + px) * 128 + khi * 16;
    }
    const uint8_t* bp = b2f + (size_t)(w * 4096 + lane * 16);
    v4i c[3][4] = {};
#pragma unroll 2
    for (int kstep = 0; kstep < 50; ++kstep) {
        int tap = kstep >> 1;
        int ky = tap / 5, kx = tap - ky * 5;
        int koff = (ky * 28 + kx) * 128 + (kstep & 1) * 64;
        v4i a0 = *(const v4i*)(acts + abase[0] + koff);
        v4i a1 = *(const v4i*)(acts + abase[1] + koff);
        v4i a2 = *(const v4i*)(acts + abase[2] + koff);
        const uint8_t* bk = bp + kstep * 8192;
#pragma unroll
        for (int o = 0; o < 4; ++o) {
            v4i b = *(const v4i*)(bk + o * 1024);
            c[0][o] = __builtin_amdgcn_mfma_i32_16x16x64_i8(a0, b, c[0][o], 0, 0, 0);
            c[1][o] = __builtin_amdgcn_mfma_i32_16x16x64_i8(a1, b, c[1][o], 0, 0, 0);
            c[2][o] = __builtin_amdgcn_mfma_i32_16x16x64_i8(a2, b, c[2][o], 0, 0, 0);
        }
    }
    // epilogue: C rows (khi*4 + reg) = pair khi, subpos reg -> pool, relu
    uint16_t* outb = rout + ((size_t)n * 144 + r * 12) * 128;
#pragma unroll
    for (int t = 0; t < 3; ++t) {
#pragma unroll
        for (int o = 0; o < 4; ++o) {
            v4i cc = c[t][o];
            int m = max(max(cc.x, cc.y), max(cc.z, cc.w));
            m = m > 0 ? m : 0;
            outb[(4 * t + khi) * 128 + (4 * w + o) * 16 + ml] = (uint16_t)m;
        }
    }
}

// ---------------- bconv3: 12x12 -> 3x3 conv -> 10x10 ----------------
__global__ __launch_bounds__(256) void bconv3_kernel(
    const uint32_t* __restrict__ actg, const uint32_t* __restrict__ wp,
    uint16_t* __restrict__ rout) {
    __shared__ __align__(16) uint32_t act[12 * 12 * 4];
    int blk = blockIdx.x;
    int n = blk >> 1, q = blk & 1;
    int tid = threadIdx.x;
    const uint32_t* src = actg + (size_t)n * 576;
    for (int i = tid; i < 576; i += 256) act[i] = src[i];
    int oc = tid & 127, s = tid >> 7;
    uint4 wreg[9];
#pragma unroll
    for (int t = 0; t < 9; ++t) wreg[t] = *(const uint4*)&wp[(t * 128 + oc) * 4];
    __syncthreads();
    for (int pp = q * 50 + s; pp < (q + 1) * 50; pp += 2) {
        int py = pp / 10, px = pp - py * 10;
        int acc = 0;
#pragma unroll
        for (int rr = 0; rr < 3; ++rr)
#pragma unroll
            for (int kx = 0; kx < 3; ++kx)
                xp4(acc, *(const uint4*)&act[((py + rr) * 12 + px + kx) * 4], wreg[rr * 3 + kx]);
        int r = 1152 - 2 * acc;
        r = r > 0 ? r : 0;
        rout[((size_t)n * 100 + pp) * 128 + oc] = (uint16_t)r;
    }
}

// ---------------- bconv4: 10x10 -> 3x3 conv -> pool -> 4x4 ----------------
__global__ __launch_bounds__(256) void bconv4_kernel(
    const uint32_t* __restrict__ actg, const uint32_t* __restrict__ wp,
    uint16_t* __restrict__ rout) {
    __shared__ __align__(16) uint32_t act[10 * 10 * 4];
    int n = blockIdx.x, tid = threadIdx.x;
    const uint32_t* src = actg + (size_t)n * 400;
    for (int i = tid; i < 400; i += 256) act[i] = src[i];
    int oc = tid & 127, s = tid >> 7;
    uint4 wreg[9];
#pragma unroll
    for (int t = 0; t < 9; ++t) wreg[t] = *(const uint4*)&wp[(t * 128 + oc) * 4];
    __syncthreads();
    for (int pp = s; pp < 16; pp += 2) {
        int py = pp >> 2, px = pp & 3;
        int cy = py * 2, cx = px * 2;
        int a00 = 0, a01 = 0, a10 = 0, a11 = 0;
#pragma unroll
        for (int rr = 0; rr < 4; ++rr) {
            uint4 rb[4];
#pragma unroll
            for (int j = 0; j < 4; ++j) rb[j] = *(const uint4*)&act[((cy + rr) * 10 + cx + j) * 4];
            if (rr <= 2) {
#pragma unroll
                for (int kx = 0; kx < 3; ++kx) {
                    uint4 wv = wreg[rr * 3 + kx];
                    xp4(a00, rb[kx], wv);
                    xp4(a01, rb[kx + 1], wv);
                }
            }
            if (rr >= 1) {
#pragma unroll
                for (int kx = 0; kx < 3; ++kx) {
                    uint4 wv = wreg[(rr - 1) * 3 + kx];
                    xp4(a10, rb[kx], wv);
                    xp4(a11, rb[kx + 1], wv);
                }
            }
        }
        int m00 = 1152 - 2 * a00, m01 = 1152 - 2 * a01;
        int m10 = 1152 - 2 * a10, m11 = 1152 - 2 * a11;
        int r = max(max(m00, m01), max(m10, m11));
        r = r > 0 ? r : 0;
        rout[((size_t)n * 16 + pp) * 128 + oc] = (uint16_t)r;
    }
}

// ---------------- fused numpy-pairwise mean + binarize (u16 in, LDS-staged) --
template <int NPOS, int NLEAF, int CHUNK, int L0, int L1, int MODE>
__global__ __launch_bounds__(256) void npmean_bin_kernel(
    const uint16_t* __restrict__ rbuf, const float* __restrict__ alpha,
    uint32_t* __restrict__ bp) {
    __shared__ uint32_t sh[NPOS * 64];
    __shared__ float ls[2 * NLEAF];
    int n = blockIdx.x, tid = threadIdx.x;
    const int NTOT = NPOS * 128;
    const uint32_t* rb32 = (const uint32_t*)(rbuf + (size_t)n * NTOT);
    for (int i = tid; i < NPOS * 64; i += 256) sh[i] = rb32[i];
    __syncthreads();
    if (tid < NLEAF) {
        int j0 = CHUNK * (tid >> 1) + ((tid & 1) ? L0 : 0);
        int len = (tid & 1) ? L1 : L0;
        float r[8];
#pragma unroll
        for (int k = 0; k < 8; ++k) {
            int j = j0 + k;
            int c = j / NPOS, p = j - c * NPOS;
            int e = p * 128 + c;
            uint32_t w = sh[e >> 1];
            float fv = (float)((e & 1) ? (w >> 16) : (w & 0xffffu));
            r[k] = mulr(alpha[c], fv);
        }
        int i = 8;
        int lim = len - (len % 8);
        for (; i < lim; i += 8) {
#pragma unroll
            for (int k = 0; k < 8; ++k) {
                int j = j0 + i + k;
                int c = j / NPOS, p = j - c * NPOS;
                int e = p * 128 + c;
                uint32_t w = sh[e >> 1];
                float fv = (float)((e & 1) ? (w >> 16) : (w & 0xffffu));
                r[k] += mulr(alpha[c], fv);
            }
        }
        float res = ((r[0] + r[1]) + (r[2] + r[3])) + ((r[4] + r[5]) + (r[6] + r[7]));
        for (; i < len; ++i) {
            int j = j0 + i;
            int c = j / NPOS, p = j - c * NPOS;
            int e = p * 128 + c;
            uint32_t w = sh[e >> 1];
            float fv = (float)((e & 1) ? (w >> 16) : (w & 0xffffu));
            res += mulr(alpha[c], fv);
        }
        ls[tid] = res;
    }
    __syncthreads();
    int src = 0, cnt = NLEAF;
    while (cnt > 1) {
        int dst = src + cnt;
        for (int i = tid; i < cnt / 2; i += 256) ls[dst + i] = ls[src + 2 * i] + ls[src + 2 * i + 1];
        __syncthreads();
        src = dst; cnt >>= 1;
    }
    float mean = ls[src] / (float)NTOT;
    if (MODE == 0) {
        for (int widx = tid; widx < NPOS * 4; widx += 256) {
            int w = widx & 3;
            uint32_t bits = 0;
#pragma unroll
            for (int i = 0; i < 32; i += 2) {
                uint32_t pw = sh[widx * 16 + (i >> 1)];
                float v0 = mulr(alpha[w * 32 + i], (float)(pw & 0xffffu));
                float v1 = mulr(alpha[w * 32 + i + 1], (float)(pw >> 16));
                bits |= (v0 > mean ? 1u : 0u) << i;
                bits |= (v1 > mean ? 1u : 0u) << (i + 1);
            }
            bp[(size_t)n * NPOS * 4 + widx] = bits;
        }
    } else {
        if (tid < 64) {
            int w = tid;
            uint32_t bits = 0;
#pragma unroll
            for (int i = 0; i < 32; ++i) {
                int f = w * 32 + i;
                int c = f >> 4, sp = f & 15;
                int e = sp * 128 + c;
                uint32_t pw = sh[e >> 1];
                float v = mulr(alpha[c], (float)((e & 1) ? (pw >> 16) : (pw & 0xffffu)));
                bits |= (v > mean ? 1u : 0u) << i;
            }
            bp[n * 64 + w] = bits;
        }
    }
}

// ---------------- binary FC ----------------
__global__ __launch_bounds__(256) void fc_kernel(
    const uint32_t* __restrict__ bxp, const uint32_t* __restrict__ fcpT,
    const float* __restrict__ bias, const float* __restrict__ alpha,
    float* __restrict__ out) {
    __shared__ uint32_t bxs[64];
    int n = blockIdx.x, tid = threadIdx.x;
    if (tid < 64) bxs[tid] = bxp[n * 64 + tid];
    __syncthreads();
    for (int o = tid; o < 512; o += 256) {
        int acc = 0;
#pragma unroll
        for (int k = 0; k < 64; ++k) acc += __popc(bxs[k] ^ fcpT[k * 512 + o]);
        float dot = (float)(2048 - 2 * acc);
        out[(size_t)n * 512 + o] = (dot + bias[o]) * alpha[o];
    }
}

extern "C" void kernel_launch(void* const* d_in, const int* in_sizes, int n_in,
                              void* d_out, int out_size, void* d_ws, size_t ws_size,
                              hipStream_t stream) {
    const float* x   = (const float*)d_in[0];
    const float* w1  = (const float*)d_in[1];
    const float* w2  = (const float*)d_in[2];
    const float* a2  = (const float*)d_in[3];
    const float* w3  = (const float*)d_in[4];
    const float* a3  = (const float*)d_in[5];
    const float* w4  = (const float*)d_in[6];
    const float* a4  = (const float*)d_in[7];
    const float* wfc = (const float*)d_in[8];
    const float* bfc = (const float*)d_in[9];
    const float* afc = (const float*)d_in[10];
    float* out = (float*)d_out;
    char* ws = (char*)d_ws;

    uint32_t* w2f = (uint32_t*)(ws + OFF_W2F);
    uint32_t* w3p = (uint32_t*)(ws + OFF_W3P);
    uint32_t* w4p = (uint32_t*)(ws + OFF_W4P);
    uint32_t* fcp = (uint32_t*)(ws + OFF_FCP);
    float*    mean1 = (float*)(ws + OFF_STAT);
    int*      zcnt  = (int*)(ws + OFF_STAT + 8192);
    int*      zlist = (int*)(ws + OFF_STAT + 10240);
    uint32_t* b1p = (uint32_t*)(ws + OFF_B1P);
    uint16_t* h2  = (uint16_t*)(ws + OFF_H2);
    uint32_t* b2p = (uint32_t*)(ws + OFF_B2P);
    uint16_t* h3  = (uint16_t*)(ws + OFF_H3);
    uint32_t* b3p = (uint32_t*)(ws + OFF_B3P);
    uint16_t* h4  = (uint16_t*)(ws + OFF_H4);
    uint32_t* bxp = (uint32_t*)(ws + OFF_BXP);

    pack_w2_frag<<<400, 256, 0, stream>>>(w2, w2f);
    pack_conv_w<<<(128 * 9 + 255) / 256, 256, 0, stream>>>(w3, w3p, 9);
    pack_conv_w<<<(128 * 9 + 255) / 256, 256, 0, stream>>>(w4, w4p, 9);
    pack_fc_w<<<2, 256, 0, stream>>>(wfc, fcp);

    conv1_mean<<<BATCH, 256, 0, stream>>>(x, w1, mean1, zcnt);
    conv1_bin<<<BATCH, 256, 0, stream>>>(x, w1, mean1, b1p, zcnt, zlist);

    bconv2_mfma<<<BATCH * 12, 128, 0, stream>>>(b1p, (const uint8_t*)w2f, h2, zcnt, zlist);
    npmean_bin_kernel<144, 256, 144, 72, 72, 0><<<BATCH, 256, 0, stream>>>(h2, a2, b2p);

    bconv3_kernel<<<BATCH * 2, 256, 0, stream>>>(b2p, w3p, h3);
    npmean_bin_kernel<100, 128, 200, 96, 104, 0><<<BATCH, 256, 0, stream>>>(h3, a3, b3p);

    bconv4_kernel<<<BATCH, 256, 0, stream>>>(b3p, w4p, h4);
    npmean_bin_kernel<16, 16, 256, 128, 128, 1><<<BATCH, 256, 0, stream>>>(h4, a4, bxp);

    fc_kernel<<<BATCH, 256, 0, stream>>>(bxp, fcp, bfc, afc, out);
}

// Round 14
// 681.146 us; speedup vs baseline: 1.4565x; 1.0270x over previous
//
#include <hip/hip_runtime.h>
#include <stdint.h>

#define BATCH 512
#define MAXZ 3

typedef int v4i __attribute__((ext_vector_type(4)));

// ---- workspace layout (bytes) ----
static const size_t OFF_W2F  = 0;          // 50*8*64*16 i8 B-frags = 409600
static const size_t OFF_W3P  = 409600;     // 9*128*4 u32
static const size_t OFF_W4P  = 428032;
static const size_t OFF_FCP  = 446464;     // 64*512 u32
static const size_t OFF_STAT = 577536;     // mean1 f32[512]@0; csum f32[512*128]@4096? -> see below
static const size_t OFF_CSUM = 577536 + 262144;  // placed after STAT block
static const size_t OFF_B1P  = 1101824;    // 512*784*16
static const size_t OFF_H2   = 7524352;    // 512*144*128*2 u16
static const size_t OFF_B2P  = 26398720;   // 512*144*16
static const size_t OFF_H3   = 27578368;   // 512*100*128*2 u16
static const size_t OFF_B3P  = 40685568;   // 512*100*16
static const size_t OFF_H4   = 41504768;   // 512*16*128*2 u16
static const size_t OFF_BXP  = 43601920;   // 512*64*4
// end ~43.9 MB

// STAT sublayout: mean1 f32[512]@+0; zcnt int[512]@+8192; zlist int[512*3]@+10240
// CSUM: per-sample 128 channel sums (f32) for the numpy pairwise tree.

// Numerics model (validated r8-r13, absmax=0): conv1 = np.einsum f32 SSE2
// order; means = numpy pairwise-f32 (leaf geometry + adjacent-pair tree);
// conv2 = i8 MFMA with act in {-1,0,+1} (0 = sign-tie); layers 3/4 exact
// integer xnor-popcount; all counts exact in u16.

__device__ inline float mulr(float a, float b) {
    float t = a * b;
    asm volatile("" : "+v"(t));
    return t;
}

__device__ inline void xp4(int& acc, uint4 a, uint4 b) {
    acc += __popc(a.x ^ b.x);
    acc += __popc(a.y ^ b.y);
    acc += __popc(a.z ^ b.z);
    acc += __popc(a.w ^ b.w);
}

// einsum SSE2-order 25-tap dot + relu over an image row-window (stride 32).
__device__ inline float einsum25_img(const float* __restrict__ ib,
                                     const float* __restrict__ wr) {
#pragma clang fp contract(off)
    float l0 = wr[0] * ib[0];
    float l1 = wr[1] * ib[1];
    float l2 = wr[2] * ib[2];
    float l3 = wr[3] * ib[3];
#pragma unroll
    for (int t = 1; t < 6; ++t) {
        int k0 = 4 * t;
#pragma unroll
        for (int u = 0; u < 4; ++u) {
            int k = k0 + u;
            int ky = k / 5, kx = k - ky * 5;
            float p = wr[k] * ib[ky * 32 + kx];
            if (u == 0) l0 += p; else if (u == 1) l1 += p;
            else if (u == 2) l2 += p; else l3 += p;
        }
    }
    float acc = (l0 + l1) + (l2 + l3);
    acc += wr[24] * ib[4 * 32 + 4];
    return acc > 0.f ? acc : 0.f;
}

// ---------------- weight packing ----------------
__global__ void pack_conv_w(const float* __restrict__ w, uint32_t* __restrict__ wp, int taps) {
    int idx = blockIdx.x * 256 + threadIdx.x;
    if (idx >= 128 * taps) return;
    int oc = idx / taps, t = idx - oc * taps;
    uint32_t words[4] = {0u, 0u, 0u, 0u};
    for (int ic = 0; ic < 128; ++ic) {
        float v = w[(size_t)(oc * 128 + ic) * taps + t];
        if (v > 0.f) words[ic >> 5] |= 1u << (ic & 31);
    }
#pragma unroll
    for (int k = 0; k < 4; ++k) wp[((size_t)t * 128 + oc) * 4 + k] = words[k];
}

__global__ void pack_w2_frag(const float* __restrict__ w2, uint32_t* __restrict__ b2f) {
    int d = blockIdx.x * 256 + threadIdx.x;   // dword index, total 102400
    if (d >= 102400) return;
    int j4 = d & 3;
    int lane = (d >> 2) & 63;
    int ok = d >> 8;
    int octile = ok & 7, kstep = ok >> 3;
    int oc = octile * 16 + (lane & 15);
    uint32_t dv = 0;
#pragma unroll
    for (int jj = 0; jj < 4; ++jj) {
        int j = j4 * 4 + jj;
        int k = kstep * 64 + (lane >> 4) * 16 + j;
        int tap = k >> 7, ch = k & 127;
        uint32_t byte = (w2[(size_t)(oc * 128 + ch) * 25 + tap] > 0.f) ? 0x01u : 0xFFu;
        dv |= byte << (8 * jj);
    }
    b2f[d] = dv;
}

__global__ void pack_fc_w(const float* __restrict__ w, uint32_t* __restrict__ wp) {
    int o = blockIdx.x * 256 + threadIdx.x;
    if (o >= 512) return;
    for (int k = 0; k < 64; ++k) {
        uint32_t bits = 0;
        for (int i = 0; i < 32; ++i)
            bits |= (w[(size_t)o * 2048 + k * 32 + i] > 0.f ? 1u : 0u) << i;
        wp[k * 512 + o] = bits;
    }
}

// ---------------- conv1 channel sums: grid (n, 16-ch group) ----------------
// Leaf geometry per channel (numpy pairwise over 784): offsets
// {0,96,192,288,392,488,584,680}, lens {96,96,96,104}x2. Lane (seg,k) owns
// chain k of leaf seg; chains/leaf/channel combine via xor-shuffles in exact
// adjacent-pair order (validated r9-r13 bit-identical).
__global__ __launch_bounds__(256) void conv1_csum(
    const float* __restrict__ x, const float* __restrict__ w1,
    float* __restrict__ csum) {
    __shared__ float img[1024];
    int blk = blockIdx.x;
    int n = blk >> 3, g = blk & 7;
    int tid = threadIdx.x;
    for (int i = tid; i < 1024; i += 256) img[i] = x[(size_t)n * 1024 + i];
    __syncthreads();
    int wave = tid >> 6, lane = tid & 63;
    int seg = lane >> 3, k = lane & 7;
    int soff = seg * 96 + (seg >= 4 ? 8 : 0);
    int strips = ((seg & 3) == 3) ? 13 : 12;
#pragma unroll
    for (int it = 0; it < 4; ++it) {
        int c = g * 16 + wave * 4 + it;
        const float* wr = w1 + c * 25;
        int p = soff + k;
        int y = p / 28, xx = p - y * 28;
        float r = einsum25_img(&img[y * 32 + xx], wr);
        for (int i = 1; i < strips; ++i) {
            p = soff + 8 * i + k;
            y = p / 28; xx = p - y * 28;
            r += einsum25_img(&img[y * 32 + xx], wr);
        }
        r = r + __shfl_xor(r, 1);
        r = r + __shfl_xor(r, 2);
        r = r + __shfl_xor(r, 4);   // leaf sum
        r = r + __shfl_xor(r, 8);
        r = r + __shfl_xor(r, 16);
        r = r + __shfl_xor(r, 32);  // channel sum
        if (lane == 0) csum[n * 128 + c] = r;
    }
}

// ---------------- conv1 tree: 128-channel adjacent-pair tree -> mean ------
__global__ __launch_bounds__(128) void conv1_tree(
    const float* __restrict__ csum, float* __restrict__ mean1,
    int* __restrict__ zcnt) {
    __shared__ float tree[256];
    int n = blockIdx.x, tid = threadIdx.x;
    tree[tid] = csum[n * 128 + tid];
    __syncthreads();
    int src = 0, cnt = 128;
    while (cnt > 1) {
        int dst = src + cnt;
        for (int i = tid; i < cnt / 2; i += 128) tree[dst + i] = tree[src + 2 * i] + tree[src + 2 * i + 1];
        __syncthreads();
        src = dst; cnt >>= 1;
    }
    if (tid == 0) { mean1[n] = tree[src] / 100352.0f; zcnt[n] = 0; }
}

// ---------------- conv1 binarize + pack; grid (n, quarter) ----------------
__global__ __launch_bounds__(256) void conv1_bin(
    const float* __restrict__ x, const float* __restrict__ w1,
    const float* __restrict__ mean1, uint32_t* __restrict__ b1p,
    int* __restrict__ zcnt, int* __restrict__ zlist) {
    __shared__ float img[1024];
    int blk = blockIdx.x;
    int n = blk >> 2, q = blk & 3;
    int tid = threadIdx.x;
    for (int i = tid; i < 1024; i += 256) img[i] = x[(size_t)n * 1024 + i];
    __syncthreads();
    float mean = mean1[n];
    int p = q * 196 + tid;
    if (tid < 196) {
        int y = p / 28, xx = p - y * 28;
        const float* ib = &img[y * 32 + xx];
        uint32_t words[4] = {0u, 0u, 0u, 0u};
#pragma unroll 2
        for (int c = 0; c < 128; ++c) {
            float h = einsum25_img(ib, w1 + c * 25);
            if (h > mean) words[c >> 5] |= 1u << (c & 31);
            else if (h == mean) {
                int kz = atomicAdd(&zcnt[n], 1);
                if (kz < MAXZ) zlist[n * MAXZ + kz] = p * 128 + c;
            }
        }
#pragma unroll
        for (int k = 0; k < 4; ++k) b1p[((size_t)n * 784 + p) * 4 + k] = words[k];
    }
}

// ---------------- bconv2 via i8 MFMA (validated r13) ----------------
__global__ __launch_bounds__(128) void bconv2_mfma(
    const uint32_t* __restrict__ b1p, const uint8_t* __restrict__ b2f,
    uint16_t* __restrict__ rout, const int* __restrict__ zcnt,
    const int* __restrict__ zlist) {
    __shared__ __align__(16) uint32_t acts32[5376];   // 6*28*128 i8
    uint8_t* acts = (uint8_t*)acts32;
    int blk = blockIdx.x;
    int n = blk / 12, r = blk - n * 12;
    int tid = threadIdx.x;
    const uint32_t* bsrc = b1p + ((size_t)n * 784 + 2 * r * 28) * 4;
    for (int d = tid; d < 5376; d += 128) {
        int pos = d >> 5;
        int nibidx = d & 31;
        uint32_t word = bsrc[pos * 4 + (nibidx >> 3)];
        uint32_t nib = (word >> ((nibidx & 7) * 4)) & 0xF;
        uint32_t spread = (nib * 0x00204081u) & 0x01010101u;
        acts32[d] = ~(spread * 0xFEu);
    }
    __syncthreads();
    if (tid == 0) {
        int nz = zcnt[n]; nz = nz > MAXZ ? MAXZ : nz;
        for (int i = 0; i < nz; ++i) {
            int e = zlist[n * MAXZ + i];
            int p = e >> 7, zc = e & 127;
            int zy = p / 28, zx = p - zy * 28;
            int ry = zy - 2 * r;
            if (ry >= 0 && ry < 6) acts[(ry * 28 + zx) * 128 + zc] = 0;
        }
    }
    __syncthreads();

    int lane = tid & 63, w = tid >> 6;
    int ml = lane & 15, khi = lane >> 4;
    int pairl = ml >> 2, dy = (ml >> 1) & 1, dx = ml & 1;
    int abase[3];
#pragma unroll
    for (int t = 0; t < 3; ++t) {
        int px = 2 * (4 * t + pairl) + dx;
        abase[t] = (dy * 28 + px) * 128 + khi * 16;
    }
    const uint8_t* bp = b2f + (size_t)(w * 4096 + lane * 16);
    v4i c[3][4] = {};
#pragma unroll 2
    for (int kstep = 0; kstep < 50; ++kstep) {
        int tap = kstep >> 1;
        int ky = tap / 5, kx = tap - ky * 5;
        int koff = (ky * 28 + kx) * 128 + (kstep & 1) * 64;
        v4i a0 = *(const v4i*)(acts + abase[0] + koff);
        v4i a1 = *(const v4i*)(acts + abase[1] + koff);
        v4i a2 = *(const v4i*)(acts + abase[2] + koff);
        const uint8_t* bk = bp + kstep * 8192;
#pragma unroll
        for (int o = 0; o < 4; ++o) {
            v4i b = *(const v4i*)(bk + o * 1024);
            c[0][o] = __builtin_amdgcn_mfma_i32_16x16x64_i8(a0, b, c[0][o], 0, 0, 0);
            c[1][o] = __builtin_amdgcn_mfma_i32_16x16x64_i8(a1, b, c[1][o], 0, 0, 0);
            c[2][o] = __builtin_amdgcn_mfma_i32_16x16x64_i8(a2, b, c[2][o], 0, 0, 0);
        }
    }
    uint16_t* outb = rout + ((size_t)n * 144 + r * 12) * 128;
#pragma unroll
    for (int t = 0; t < 3; ++t) {
#pragma unroll
        for (int o = 0; o < 4; ++o) {
            v4i cc = c[t][o];
            int m = max(max(cc.x, cc.y), max(cc.z, cc.w));
            m = m > 0 ? m : 0;
            outb[(4 * t + khi) * 128 + (4 * w + o) * 16 + ml] = (uint16_t)m;
        }
    }
}

// ---------------- bconv3: 12x12 -> 3x3 conv -> 10x10 ----------------
__global__ __launch_bounds__(256) void bconv3_kernel(
    const uint32_t* __restrict__ actg, const uint32_t* __restrict__ wp,
    uint16_t* __restrict__ rout) {
    __shared__ __align__(16) uint32_t act[12 * 12 * 4];
    int blk = blockIdx.x;
    int n = blk >> 1, q = blk & 1;
    int tid = threadIdx.x;
    const uint32_t* src = actg + (size_t)n * 576;
    for (int i = tid; i < 576; i += 256) act[i] = src[i];
    int oc = tid & 127, s = tid >> 7;
    uint4 wreg[9];
#pragma unroll
    for (int t = 0; t < 9; ++t) wreg[t] = *(const uint4*)&wp[(t * 128 + oc) * 4];
    __syncthreads();
    for (int pp = q * 50 + s; pp < (q + 1) * 50; pp += 2) {
        int py = pp / 10, px = pp - py * 10;
        int acc = 0;
#pragma unroll
        for (int rr = 0; rr < 3; ++rr)
#pragma unroll
            for (int kx = 0; kx < 3; ++kx)
                xp4(acc, *(const uint4*)&act[((py + rr) * 12 + px + kx) * 4], wreg[rr * 3 + kx]);
        int r = 1152 - 2 * acc;
        r = r > 0 ? r : 0;
        rout[((size_t)n * 100 + pp) * 128 + oc] = (uint16_t)r;
    }
}

// ---------------- bconv4: 10x10 -> 3x3 conv -> pool -> 4x4 ----------------
__global__ __launch_bounds__(256) void bconv4_kernel(
    const uint32_t* __restrict__ actg, const uint32_t* __restrict__ wp,
    uint16_t* __restrict__ rout) {
    __shared__ __align__(16) uint32_t act[10 * 10 * 4];
    int n = blockIdx.x, tid = threadIdx.x;
    const uint32_t* src = actg + (size_t)n * 400;
    for (int i = tid; i < 400; i += 256) act[i] = src[i];
    int oc = tid & 127, s = tid >> 7;
    uint4 wreg[9];
#pragma unroll
    for (int t = 0; t < 9; ++t) wreg[t] = *(const uint4*)&wp[(t * 128 + oc) * 4];
    __syncthreads();
    for (int pp = s; pp < 16; pp += 2) {
        int py = pp >> 2, px = pp & 3;
        int cy = py * 2, cx = px * 2;
        int a00 = 0, a01 = 0, a10 = 0, a11 = 0;
#pragma unroll
        for (int rr = 0; rr < 4; ++rr) {
            uint4 rb[4];
#pragma unroll
            for (int j = 0; j < 4; ++j) rb[j] = *(const uint4*)&act[((cy + rr) * 10 + cx + j) * 4];
            if (rr <= 2) {
#pragma unroll
                for (int kx = 0; kx < 3; ++kx) {
                    uint4 wv = wreg[rr * 3 + kx];
                    xp4(a00, rb[kx], wv);
                    xp4(a01, rb[kx + 1], wv);
                }
            }
            if (rr >= 1) {
#pragma unroll
                for (int kx = 0; kx < 3; ++kx) {
                    uint4 wv = wreg[(rr - 1) * 3 + kx];
                    xp4(a10, rb[kx], wv);
                    xp4(a11, rb[kx + 1], wv);
                }
            }
        }
        int m00 = 1152 - 2 * a00, m01 = 1152 - 2 * a01;
        int m10 = 1152 - 2 * a10, m11 = 1152 - 2 * a11;
        int r = max(max(m00, m01), max(m10, m11));
        r = r > 0 ? r : 0;
        rout[((size_t)n * 16 + pp) * 128 + oc] = (uint16_t)r;
    }
}

// ---------------- fused numpy-pairwise mean + binarize (u16 in, LDS-staged) --
template <int NPOS, int NLEAF, int CHUNK, int L0, int L1, int MODE>
__global__ __launch_bounds__(256) void npmean_bin_kernel(
    const uint16_t* __restrict__ rbuf, const float* __restrict__ alpha,
    uint32_t* __restrict__ bp) {
    __shared__ uint32_t sh[NPOS * 64];
    __shared__ float ls[2 * NLEAF];
    int n = blockIdx.x, tid = threadIdx.x;
    const int NTOT = NPOS * 128;
    const uint32_t* rb32 = (const uint32_t*)(rbuf + (size_t)n * NTOT);
    for (int i = tid; i < NPOS * 64; i += 256) sh[i] = rb32[i];
    __syncthreads();
    if (tid < NLEAF) {
        int j0 = CHUNK * (tid >> 1) + ((tid & 1) ? L0 : 0);
        int len = (tid & 1) ? L1 : L0;
        float r[8];
#pragma unroll
        for (int k = 0; k < 8; ++k) {
            int j = j0 + k;
            int c = j / NPOS, p = j - c * NPOS;
            int e = p * 128 + c;
            uint32_t w = sh[e >> 1];
            float fv = (float)((e & 1) ? (w >> 16) : (w & 0xffffu));
            r[k] = mulr(alpha[c], fv);
        }
        int i = 8;
        int lim = len - (len % 8);
        for (; i < lim; i += 8) {
#pragma unroll
            for (int k = 0; k < 8; ++k) {
                int j = j0 + i + k;
                int c = j / NPOS, p = j - c * NPOS;
                int e = p * 128 + c;
                uint32_t w = sh[e >> 1];
                float fv = (float)((e & 1) ? (w >> 16) : (w & 0xffffu));
                r[k] += mulr(alpha[c], fv);
            }
        }
        float res = ((r[0] + r[1]) + (r[2] + r[3])) + ((r[4] + r[5]) + (r[6] + r[7]));
        for (; i < len; ++i) {
            int j = j0 + i;
            int c = j / NPOS, p = j - c * NPOS;
            int e = p * 128 + c;
            uint32_t w = sh[e >> 1];
            float fv = (float)((e & 1) ? (w >> 16) : (w & 0xffffu));
            res += mulr(alpha[c], fv);
        }
        ls[tid] = res;
    }
    __syncthreads();
    int src = 0, cnt = NLEAF;
    while (cnt > 1) {
        int dst = src + cnt;
        for (int i = tid; i < cnt / 2; i += 256) ls[dst + i] = ls[src + 2 * i] + ls[src + 2 * i + 1];
        __syncthreads();
        src = dst; cnt >>= 1;
    }
    float mean = ls[src] / (float)NTOT;
    if (MODE == 0) {
        for (int widx = tid; widx < NPOS * 4; widx += 256) {
            int w = widx & 3;
            uint32_t bits = 0;
#pragma unroll
            for (int i = 0; i < 32; i += 2) {
                uint32_t pw = sh[widx * 16 + (i >> 1)];
                float v0 = mulr(alpha[w * 32 + i], (float)(pw & 0xffffu));
                float v1 = mulr(alpha[w * 32 + i + 1], (float)(pw >> 16));
                bits |= (v0 > mean ? 1u : 0u) << i;
                bits |= (v1 > mean ? 1u : 0u) << (i + 1);
            }
            bp[(size_t)n * NPOS * 4 + widx] = bits;
        }
    } else {
        if (tid < 64) {
            int w = tid;
            uint32_t bits = 0;
#pragma unroll
            for (int i = 0; i < 32; ++i) {
                int f = w * 32 + i;
                int c = f >> 4, sp = f & 15;
                int e = sp * 128 + c;
                uint32_t pw = sh[e >> 1];
                float v = mulr(alpha[c], (float)((e & 1) ? (pw >> 16) : (pw & 0xffffu)));
                bits |= (v > mean ? 1u : 0u) << i;
            }
            bp[n * 64 + w] = bits;
        }
    }
}

// ---------------- binary FC ----------------
__global__ __launch_bounds__(256) void fc_kernel(
    const uint32_t* __restrict__ bxp, const uint32_t* __restrict__ fcpT,
    const float* __restrict__ bias, const float* __restrict__ alpha,
    float* __restrict__ out) {
    __shared__ uint32_t bxs[64];
    int n = blockIdx.x, tid = threadIdx.x;
    if (tid < 64) bxs[tid] = bxp[n * 64 + tid];
    __syncthreads();
    for (int o = tid; o < 512; o += 256) {
        int acc = 0;
#pragma unroll
        for (int k = 0; k < 64; ++k) acc += __popc(bxs[k] ^ fcpT[k * 512 + o]);
        float dot = (float)(2048 - 2 * acc);
        out[(size_t)n * 512 + o] = (dot + bias[o]) * alpha[o];
    }
}

extern "C" void kernel_launch(void* const* d_in, const int* in_sizes, int n_in,
                              void* d_out, int out_size, void* d_ws, size_t ws_size,
                              hipStream_t stream) {
    const float* x   = (const float*)d_in[0];
    const float* w1  = (const float*)d_in[1];
    const float* w2  = (const float*)d_in[2];
    const float* a2  = (const float*)d_in[3];
    const float* w3  = (const float*)d_in[4];
    const float* a3  = (const float*)d_in[5];
    const float* w4  = (const float*)d_in[6];
    const float* a4  = (const float*)d_in[7];
    const float* wfc = (const float*)d_in[8];
    const float* bfc = (const float*)d_in[9];
    const float* afc = (const float*)d_in[10];
    float* out = (float*)d_out;
    char* ws = (char*)d_ws;

    uint32_t* w2f = (uint32_t*)(ws + OFF_W2F);
    uint32_t* w3p = (uint32_t*)(ws + OFF_W3P);
    uint32_t* w4p = (uint32_t*)(ws + OFF_W4P);
    uint32_t* fcp = (uint32_t*)(ws + OFF_FCP);
    float*    mean1 = (float*)(ws + OFF_STAT);
    int*      zcnt  = (int*)(ws + OFF_STAT + 8192);
    int*      zlist = (int*)(ws + OFF_STAT + 10240);
    float*    csum  = (float*)(ws + OFF_CSUM);
    uint32_t* b1p = (uint32_t*)(ws + OFF_B1P);
    uint16_t* h2  = (uint16_t*)(ws + OFF_H2);
    uint32_t* b2p = (uint32_t*)(ws + OFF_B2P);
    uint16_t* h3  = (uint16_t*)(ws + OFF_H3);
    uint32_t* b3p = (uint32_t*)(ws + OFF_B3P);
    uint16_t* h4  = (uint16_t*)(ws + OFF_H4);
    uint32_t* bxp = (uint32_t*)(ws + OFF_BXP);

    pack_w2_frag<<<400, 256, 0, stream>>>(w2, w2f);
    pack_conv_w<<<(128 * 9 + 255) / 256, 256, 0, stream>>>(w3, w3p, 9);
    pack_conv_w<<<(128 * 9 + 255) / 256, 256, 0, stream>>>(w4, w4p, 9);
    pack_fc_w<<<2, 256, 0, stream>>>(wfc, fcp);

    conv1_csum<<<BATCH * 8, 256, 0, stream>>>(x, w1, csum);
    conv1_tree<<<BATCH, 128, 0, stream>>>(csum, mean1, zcnt);
    conv1_bin<<<BATCH * 4, 256, 0, stream>>>(x, w1, mean1, b1p, zcnt, zlist);

    bconv2_mfma<<<BATCH * 12, 128, 0, stream>>>(b1p, (const uint8_t*)w2f, h2, zcnt, zlist);
    npmean_bin_kernel<144, 256, 144, 72, 72, 0><<<BATCH, 256, 0, stream>>>(h2, a2, b2p);

    bconv3_kernel<<<BATCH * 2, 256, 0, stream>>>(b2p, w3p, h3);
    npmean_bin_kernel<100, 128, 200, 96, 104, 0><<<BATCH, 256, 0, stream>>>(h3, a3, b3p);

    bconv4_kernel<<<BATCH, 256, 0, stream>>>(b3p, w4p, h4);
    npmean_bin_kernel<16, 16, 256, 128, 128, 1><<<BATCH, 256, 0, stream>>>(h4, a4, bxp);

    fc_kernel<<<BATCH, 256, 0, stream>>>(bxp, fcp, bfc, afc, out);
}

// Round 15
// 604.670 us; speedup vs baseline: 1.6408x; 1.1265x over previous
//
#include <hip/hip_runtime.h>
#include <stdint.h>

#define BATCH 512
#define MAXZ 3

typedef int v4i __attribute__((ext_vector_type(4)));

// ---- workspace layout (bytes) ----
static const size_t OFF_W2F  = 0;          // 50*8*64*16 i8 B-frags = 409600
static const size_t OFF_W3P  = 409600;     // 9*128*4 u32
static const size_t OFF_W4P  = 428032;
static const size_t OFF_FCP  = 446464;     // 64*512 u32
static const size_t OFF_STAT = 577536;     // mean1 f32[512]@0; zcnt@8192; zlist@10240
static const size_t OFF_CSUM = 839680;     // 512*128 f32
static const size_t OFF_B1P  = 1101824;    // 512*784*16
static const size_t OFF_H2   = 7524352;    // 512*144*128*2 u16
static const size_t OFF_B2P  = 26398720;   // 512*144*16
static const size_t OFF_H3   = 27578368;   // 512*100*128*2 u16
static const size_t OFF_B3P  = 40685568;   // 512*100*16
static const size_t OFF_H4   = 41504768;   // 512*16*128*2 u16
static const size_t OFF_BXP  = 43601920;   // 512*64*4
// end ~43.9 MB

// Numerics model (validated r8-r14, absmax=0): conv1 = np.einsum f32 SSE2
// order; means = numpy pairwise-f32 (leaf geometry + adjacent-pair tree);
// conv2 = i8 MFMA with act in {-1,0,+1} (0 = sign-tie); layers 3/4 exact
// integer xnor-popcount; all counts exact in u16.

__device__ inline float mulr(float a, float b) {
    float t = a * b;
    asm volatile("" : "+v"(t));
    return t;
}

__device__ inline void xp4(int& acc, uint4 a, uint4 b) {
    acc += __popc(a.x ^ b.x);
    acc += __popc(a.y ^ b.y);
    acc += __popc(a.z ^ b.z);
    acc += __popc(a.w ^ b.w);
}

// einsum SSE2-order 25-tap dot + relu on a register patch (validated r8).
__device__ inline float einsum25(const float* __restrict__ patch,
                                 const float* __restrict__ wr) {
#pragma clang fp contract(off)
    float l0 = wr[0] * patch[0];
    float l1 = wr[1] * patch[1];
    float l2 = wr[2] * patch[2];
    float l3 = wr[3] * patch[3];
#pragma unroll
    for (int t = 1; t < 6; ++t) {
        l0 += wr[4 * t + 0] * patch[4 * t + 0];
        l1 += wr[4 * t + 1] * patch[4 * t + 1];
        l2 += wr[4 * t + 2] * patch[4 * t + 2];
        l3 += wr[4 * t + 3] * patch[4 * t + 3];
    }
    float acc = (l0 + l1) + (l2 + l3);
    acc += wr[24] * patch[24];
    return acc > 0.f ? acc : 0.f;
}

// ---------------- weight packing ----------------
__global__ void pack_conv_w(const float* __restrict__ w, uint32_t* __restrict__ wp, int taps) {
    int idx = blockIdx.x * 256 + threadIdx.x;
    if (idx >= 128 * taps) return;
    int oc = idx / taps, t = idx - oc * taps;
    uint32_t words[4] = {0u, 0u, 0u, 0u};
    for (int ic = 0; ic < 128; ++ic) {
        float v = w[(size_t)(oc * 128 + ic) * taps + t];
        if (v > 0.f) words[ic >> 5] |= 1u << (ic & 31);
    }
#pragma unroll
    for (int k = 0; k < 4; ++k) wp[((size_t)t * 128 + oc) * 4 + k] = words[k];
}

__global__ void pack_w2_frag(const float* __restrict__ w2, uint32_t* __restrict__ b2f) {
    int d = blockIdx.x * 256 + threadIdx.x;   // dword index, total 102400
    if (d >= 102400) return;
    int j4 = d & 3;
    int lane = (d >> 2) & 63;
    int ok = d >> 8;
    int octile = ok & 7, kstep = ok >> 3;
    int oc = octile * 16 + (lane & 15);
    uint32_t dv = 0;
#pragma unroll
    for (int jj = 0; jj < 4; ++jj) {
        int j = j4 * 4 + jj;
        int k = kstep * 64 + (lane >> 4) * 16 + j;
        int tap = k >> 7, ch = k & 127;
        uint32_t byte = (w2[(size_t)(oc * 128 + ch) * 25 + tap] > 0.f) ? 0x01u : 0xFFu;
        dv |= byte << (8 * jj);
    }
    b2f[d] = dv;
}

__global__ void pack_fc_w(const float* __restrict__ w, uint32_t* __restrict__ wp) {
    int o = blockIdx.x * 256 + threadIdx.x;
    if (o >= 512) return;
    for (int k = 0; k < 64; ++k) {
        uint32_t bits = 0;
        for (int i = 0; i < 32; ++i)
            bits |= (w[(size_t)o * 2048 + k * 32 + i] > 0.f ? 1u : 0u) << i;
        wp[k * 512 + o] = bits;
    }
}

// ---------------- conv1 channel sums: grid (n, 16-ch group) ----------------
// Loop-interchanged: patch -> registers once per strip, 4 channels evaluated
// per patch (LDS reads /4). img padded to stride 33 (bank de-alias).
// Chain accumulation order identical to r9-r14 (bit-exact).
__global__ __launch_bounds__(256) void conv1_csum(
    const float* __restrict__ x, const float* __restrict__ w1,
    float* __restrict__ csum) {
    __shared__ float img[32 * 33];
    int blk = blockIdx.x;
    int n = blk >> 3, g = blk & 7;
    int tid = threadIdx.x;
    for (int i = tid; i < 1024; i += 256) {
        int y = i >> 5, xx = i & 31;
        img[y * 33 + xx] = x[(size_t)n * 1024 + i];
    }
    __syncthreads();
    int wave = tid >> 6, lane = tid & 63;
    int seg = lane >> 3, k = lane & 7;
    int soff = seg * 96 + (seg >= 4 ? 8 : 0);
    int strips = ((seg & 3) == 3) ? 13 : 12;
    int c0 = g * 16 + wave * 4;
    float wreg[4][25];
#pragma unroll
    for (int it = 0; it < 4; ++it)
#pragma unroll
        for (int t = 0; t < 25; ++t) wreg[it][t] = w1[(c0 + it) * 25 + t];
    float racc[4];
    for (int i = 0; i < strips; ++i) {
        int p = soff + 8 * i + k;
        int y = p / 28, xx = p - y * 28;
        const float* ib = &img[y * 33 + xx];
        float patch[25];
#pragma unroll
        for (int ky = 0; ky < 5; ++ky)
#pragma unroll
            for (int kx = 0; kx < 5; ++kx)
                patch[ky * 5 + kx] = ib[ky * 33 + kx];
#pragma unroll
        for (int it = 0; it < 4; ++it) {
            float h = einsum25(patch, wreg[it]);
            racc[it] = (i == 0) ? h : racc[it] + h;
        }
    }
#pragma unroll
    for (int it = 0; it < 4; ++it) {
        float r = racc[it];
        r = r + __shfl_xor(r, 1);
        r = r + __shfl_xor(r, 2);
        r = r + __shfl_xor(r, 4);   // leaf sum
        r = r + __shfl_xor(r, 8);
        r = r + __shfl_xor(r, 16);
        r = r + __shfl_xor(r, 32);  // channel sum
        if (lane == 0) csum[n * 128 + c0 + it] = r;
    }
}

// ---------------- conv1 tree: 128-channel adjacent-pair tree -> mean ------
__global__ __launch_bounds__(128) void conv1_tree(
    const float* __restrict__ csum, float* __restrict__ mean1,
    int* __restrict__ zcnt) {
    __shared__ float tree[256];
    int n = blockIdx.x, tid = threadIdx.x;
    tree[tid] = csum[n * 128 + tid];
    __syncthreads();
    int src = 0, cnt = 128;
    while (cnt > 1) {
        int dst = src + cnt;
        for (int i = tid; i < cnt / 2; i += 128) tree[dst + i] = tree[src + 2 * i] + tree[src + 2 * i + 1];
        __syncthreads();
        src = dst; cnt >>= 1;
    }
    if (tid == 0) { mean1[n] = tree[src] / 100352.0f; zcnt[n] = 0; }
}

// ---------------- conv1 binarize + pack; grid (n, quarter) ----------------
__global__ __launch_bounds__(256) void conv1_bin(
    const float* __restrict__ x, const float* __restrict__ w1,
    const float* __restrict__ mean1, uint32_t* __restrict__ b1p,
    int* __restrict__ zcnt, int* __restrict__ zlist) {
    __shared__ float img[32 * 33];
    int blk = blockIdx.x;
    int n = blk >> 2, q = blk & 3;
    int tid = threadIdx.x;
    for (int i = tid; i < 1024; i += 256) {
        int y = i >> 5, xx = i & 31;
        img[y * 33 + xx] = x[(size_t)n * 1024 + i];
    }
    __syncthreads();
    float mean = mean1[n];
    int p = q * 196 + tid;
    if (tid < 196) {
        int y = p / 28, xx = p - y * 28;
        const float* ib = &img[y * 33 + xx];
        float patch[25];
#pragma unroll
        for (int ky = 0; ky < 5; ++ky)
#pragma unroll
            for (int kx = 0; kx < 5; ++kx)
                patch[ky * 5 + kx] = ib[ky * 33 + kx];
        uint32_t words[4] = {0u, 0u, 0u, 0u};
#pragma unroll 2
        for (int c = 0; c < 128; ++c) {
            float h = einsum25(patch, w1 + c * 25);
            if (h > mean) words[c >> 5] |= 1u << (c & 31);
            else if (h == mean) {
                int kz = atomicAdd(&zcnt[n], 1);
                if (kz < MAXZ) zlist[n * MAXZ + kz] = p * 128 + c;
            }
        }
#pragma unroll
        for (int k = 0; k < 4; ++k) b1p[((size_t)n * 784 + p) * 4 + k] = words[k];
    }
}

// ---------------- bconv2 via i8 MFMA (validated r13) ----------------
__global__ __launch_bounds__(128) void bconv2_mfma(
    const uint32_t* __restrict__ b1p, const uint8_t* __restrict__ b2f,
    uint16_t* __restrict__ rout, const int* __restrict__ zcnt,
    const int* __restrict__ zlist) {
    __shared__ __align__(16) uint32_t acts32[5376];   // 6*28*128 i8
    uint8_t* acts = (uint8_t*)acts32;
    int blk = blockIdx.x;
    int n = blk / 12, r = blk - n * 12;
    int tid = threadIdx.x;
    const uint32_t* bsrc = b1p + ((size_t)n * 784 + 2 * r * 28) * 4;
    for (int d = tid; d < 5376; d += 128) {
        int pos = d >> 5;
        int nibidx = d & 31;
        uint32_t word = bsrc[pos * 4 + (nibidx >> 3)];
        uint32_t nib = (word >> ((nibidx & 7) * 4)) & 0xF;
        uint32_t spread = (nib * 0x00204081u) & 0x01010101u;
        acts32[d] = ~(spread * 0xFEu);
    }
    __syncthreads();
    if (tid == 0) {
        int nz = zcnt[n]; nz = nz > MAXZ ? MAXZ : nz;
        for (int i = 0; i < nz; ++i) {
            int e = zlist[n * MAXZ + i];
            int p = e >> 7, zc = e & 127;
            int zy = p / 28, zx = p - zy * 28;
            int ry = zy - 2 * r;
            if (ry >= 0 && ry < 6) acts[(ry * 28 + zx) * 128 + zc] = 0;
        }
    }
    __syncthreads();

    int lane = tid & 63, w = tid >> 6;
    int ml = lane & 15, khi = lane >> 4;
    int pairl = ml >> 2, dy = (ml >> 1) & 1, dx = ml & 1;
    int abase[3];
#pragma unroll
    for (int t = 0; t < 3; ++t) {
        int px = 2 * (4 * t + pairl) + dx;
        abase[t] = (dy * 28 + px) * 128 + khi * 16;
    }
    const uint8_t* bp = b2f + (size_t)(w * 4096 + lane * 16);
    v4i c[3][4] = {};
#pragma unroll 2
    for (int kstep = 0; kstep < 50; ++kstep) {
        int tap = kstep >> 1;
        int ky = tap / 5, kx = tap - ky * 5;
        int koff = (ky * 28 + kx) * 128 + (kstep & 1) * 64;
        v4i a0 = *(const v4i*)(acts + abase[0] + koff);
        v4i a1 = *(const v4i*)(acts + abase[1] + koff);
        v4i a2 = *(const v4i*)(acts + abase[2] + koff);
        const uint8_t* bk = bp + kstep * 8192;
#pragma unroll
        for (int o = 0; o < 4; ++o) {
            v4i b = *(const v4i*)(bk + o * 1024);
            c[0][o] = __builtin_amdgcn_mfma_i32_16x16x64_i8(a0, b, c[0][o], 0, 0, 0);
            c[1][o] = __builtin_amdgcn_mfma_i32_16x16x64_i8(a1, b, c[1][o], 0, 0, 0);
            c[2][o] = __builtin_amdgcn_mfma_i32_16x16x64_i8(a2, b, c[2][o], 0, 0, 0);
        }
    }
    uint16_t* outb = rout + ((size_t)n * 144 + r * 12) * 128;
#pragma unroll
    for (int t = 0; t < 3; ++t) {
#pragma unroll
        for (int o = 0; o < 4; ++o) {
            v4i cc = c[t][o];
            int m = max(max(cc.x, cc.y), max(cc.z, cc.w));
            m = m > 0 ? m : 0;
            outb[(4 * t + khi) * 128 + (4 * w + o) * 16 + ml] = (uint16_t)m;
        }
    }
}

// ---------------- bconv3: 12x12 -> 3x3 conv -> 10x10 ----------------
__global__ __launch_bounds__(256) void bconv3_kernel(
    const uint32_t* __restrict__ actg, const uint32_t* __restrict__ wp,
    uint16_t* __restrict__ rout) {
    __shared__ __align__(16) uint32_t act[12 * 12 * 4];
    int blk = blockIdx.x;
    int n = blk >> 1, q = blk & 1;
    int tid = threadIdx.x;
    const uint32_t* src = actg + (size_t)n * 576;
    for (int i = tid; i < 576; i += 256) act[i] = src[i];
    int oc = tid & 127, s = tid >> 7;
    uint4 wreg[9];
#pragma unroll
    for (int t = 0; t < 9; ++t) wreg[t] = *(const uint4*)&wp[(t * 128 + oc) * 4];
    __syncthreads();
    for (int pp = q * 50 + s; pp < (q + 1) * 50; pp += 2) {
        int py = pp / 10, px = pp - py * 10;
        int acc = 0;
#pragma unroll
        for (int rr = 0; rr < 3; ++rr)
#pragma unroll
            for (int kx = 0; kx < 3; ++kx)
                xp4(acc, *(const uint4*)&act[((py + rr) * 12 + px + kx) * 4], wreg[rr * 3 + kx]);
        int r = 1152 - 2 * acc;
        r = r > 0 ? r : 0;
        rout[((size_t)n * 100 + pp) * 128 + oc] = (uint16_t)r;
    }
}

// ---------------- bconv4: 10x10 -> 3x3 conv -> pool -> 4x4 ----------------
__global__ __launch_bounds__(256) void bconv4_kernel(
    const uint32_t* __restrict__ actg, const uint32_t* __restrict__ wp,
    uint16_t* __restrict__ rout) {
    __shared__ __align__(16) uint32_t act[10 * 10 * 4];
    int n = blockIdx.x, tid = threadIdx.x;
    const uint32_t* src = actg + (size_t)n * 400;
    for (int i = tid; i < 400; i += 256) act[i] = src[i];
    int oc = tid & 127, s = tid >> 7;
    uint4 wreg[9];
#pragma unroll
    for (int t = 0; t < 9; ++t) wreg[t] = *(const uint4*)&wp[(t * 128 + oc) * 4];
    __syncthreads();
    for (int pp = s; pp < 16; pp += 2) {
        int py = pp >> 2, px = pp & 3;
        int cy = py * 2, cx = px * 2;
        int a00 = 0, a01 = 0, a10 = 0, a11 = 0;
#pragma unroll
        for (int rr = 0; rr < 4; ++rr) {
            uint4 rb[4];
#pragma unroll
            for (int j = 0; j < 4; ++j) rb[j] = *(const uint4*)&act[((cy + rr) * 10 + cx + j) * 4];
            if (rr <= 2) {
#pragma unroll
                for (int kx = 0; kx < 3; ++kx) {
                    uint4 wv = wreg[rr * 3 + kx];
                    xp4(a00, rb[kx], wv);
                    xp4(a01, rb[kx + 1], wv);
                }
            }
            if (rr >= 1) {
#pragma unroll
                for (int kx = 0; kx < 3; ++kx) {
                    uint4 wv = wreg[(rr - 1) * 3 + kx];
                    xp4(a10, rb[kx], wv);
                    xp4(a11, rb[kx + 1], wv);
                }
            }
        }
        int m00 = 1152 - 2 * a00, m01 = 1152 - 2 * a01;
        int m10 = 1152 - 2 * a10, m11 = 1152 - 2 * a11;
        int r = max(max(m00, m01), max(m10, m11));
        r = r > 0 ? r : 0;
        rout[((size_t)n * 16 + pp) * 128 + oc] = (uint16_t)r;
    }
}

// ---------------- fused numpy-pairwise mean + binarize (u16 in, LDS-staged) --
template <int NPOS, int NLEAF, int CHUNK, int L0, int L1, int MODE>
__global__ __launch_bounds__(256) void npmean_bin_kernel(
    const uint16_t* __restrict__ rbuf, const float* __restrict__ alpha,
    uint32_t* __restrict__ bp) {
    __shared__ uint32_t sh[NPOS * 64];
    __shared__ float ls[2 * NLEAF];
    int n = blockIdx.x, tid = threadIdx.x;
    const int NTOT = NPOS * 128;
    const uint32_t* rb32 = (const uint32_t*)(rbuf + (size_t)n * NTOT);
    for (int i = tid; i < NPOS * 64; i += 256) sh[i] = rb32[i];
    __syncthreads();
    if (tid < NLEAF) {
        int j0 = CHUNK * (tid >> 1) + ((tid & 1) ? L0 : 0);
        int len = (tid & 1) ? L1 : L0;
        float r[8];
#pragma unroll
        for (int k = 0; k < 8; ++k) {
            int j = j0 + k;
            int c = j / NPOS, p = j - c * NPOS;
            int e = p * 128 + c;
            uint32_t w = sh[e >> 1];
            float fv = (float)((e & 1) ? (w >> 16) : (w & 0xffffu));
            r[k] = mulr(alpha[c], fv);
        }
        int i = 8;
        int lim = len - (len % 8);
        for (; i < lim; i += 8) {
#pragma unroll
            for (int k = 0; k < 8; ++k) {
                int j = j0 + i + k;
                int c = j / NPOS, p = j - c * NPOS;
                int e = p * 128 + c;
                uint32_t w = sh[e >> 1];
                float fv = (float)((e & 1) ? (w >> 16) : (w & 0xffffu));
                r[k] += mulr(alpha[c], fv);
            }
        }
        float res = ((r[0] + r[1]) + (r[2] + r[3])) + ((r[4] + r[5]) + (r[6] + r[7]));
        for (; i < len; ++i) {
            int j = j0 + i;
            int c = j / NPOS, p = j - c * NPOS;
            int e = p * 128 + c;
            uint32_t w = sh[e >> 1];
            float fv = (float)((e & 1) ? (w >> 16) : (w & 0xffffu));
            res += mulr(alpha[c], fv);
        }
        ls[tid] = res;
    }
    __syncthreads();
    int src = 0, cnt = NLEAF;
    while (cnt > 1) {
        int dst = src + cnt;
        for (int i = tid; i < cnt / 2; i += 256) ls[dst + i] = ls[src + 2 * i] + ls[src + 2 * i + 1];
        __syncthreads();
        src = dst; cnt >>= 1;
    }
    float mean = ls[src] / (float)NTOT;
    if (MODE == 0) {
        for (int widx = tid; widx < NPOS * 4; widx += 256) {
            int w = widx & 3;
            uint32_t bits = 0;
#pragma unroll
            for (int i = 0; i < 32; i += 2) {
                uint32_t pw = sh[widx * 16 + (i >> 1)];
                float v0 = mulr(alpha[w * 32 + i], (float)(pw & 0xffffu));
                float v1 = mulr(alpha[w * 32 + i + 1], (float)(pw >> 16));
                bits |= (v0 > mean ? 1u : 0u) << i;
                bits |= (v1 > mean ? 1u : 0u) << (i + 1);
            }
            bp[(size_t)n * NPOS * 4 + widx] = bits;
        }
    } else {
        if (tid < 64) {
            int w = tid;
            uint32_t bits = 0;
#pragma unroll
            for (int i = 0; i < 32; ++i) {
                int f = w * 32 + i;
                int c = f >> 4, sp = f & 15;
                int e = sp * 128 + c;
                uint32_t pw = sh[e >> 1];
                float v = mulr(alpha[c], (float)((e & 1) ? (pw >> 16) : (pw & 0xffffu)));
                bits |= (v > mean ? 1u : 0u) << i;
            }
            bp[n * 64 + w] = bits;
        }
    }
}

// ---------------- binary FC ----------------
__global__ __launch_bounds__(256) void fc_kernel(
    const uint32_t* __restrict__ bxp, const uint32_t* __restrict__ fcpT,
    const float* __restrict__ bias, const float* __restrict__ alpha,
    float* __restrict__ out) {
    __shared__ uint32_t bxs[64];
    int n = blockIdx.x, tid = threadIdx.x;
    if (tid < 64) bxs[tid] = bxp[n * 64 + tid];
    __syncthreads();
    for (int o = tid; o < 512; o += 256) {
        int acc = 0;
#pragma unroll
        for (int k = 0; k < 64; ++k) acc += __popc(bxs[k] ^ fcpT[k * 512 + o]);
        float dot = (float)(2048 - 2 * acc);
        out[(size_t)n * 512 + o] = (dot + bias[o]) * alpha[o];
    }
}

extern "C" void kernel_launch(void* const* d_in, const int* in_sizes, int n_in,
                              void* d_out, int out_size, void* d_ws, size_t ws_size,
                              hipStream_t stream) {
    const float* x   = (const float*)d_in[0];
    const float* w1  = (const float*)d_in[1];
    const float* w2  = (const float*)d_in[2];
    const float* a2  = (const float*)d_in[3];
    const float* w3  = (const float*)d_in[4];
    const float* a3  = (const float*)d_in[5];
    const float* w4  = (const float*)d_in[6];
    const float* a4  = (const float*)d_in[7];
    const float* wfc = (const float*)d_in[8];
    const float* bfc = (const float*)d_in[9];
    const float* afc = (const float*)d_in[10];
    float* out = (float*)d_out;
    char* ws = (char*)d_ws;

    uint32_t* w2f = (uint32_t*)(ws + OFF_W2F);
    uint32_t* w3p = (uint32_t*)(ws + OFF_W3P);
    uint32_t* w4p = (uint32_t*)(ws + OFF_W4P);
    uint32_t* fcp = (uint32_t*)(ws + OFF_FCP);
    float*    mean1 = (float*)(ws + OFF_STAT);
    int*      zcnt  = (int*)(ws + OFF_STAT + 8192);
    int*      zlist = (int*)(ws + OFF_STAT + 10240);
    float*    csum  = (float*)(ws + OFF_CSUM);
    uint32_t* b1p = (uint32_t*)(ws + OFF_B1P);
    uint16_t* h2  = (uint16_t*)(ws + OFF_H2);
    uint32_t* b2p = (uint32_t*)(ws + OFF_B2P);
    uint16_t* h3  = (uint16_t*)(ws + OFF_H3);
    uint32_t* b3p = (uint32_t*)(ws + OFF_B3P);
    uint16_t* h4  = (uint16_t*)(ws + OFF_H4);
    uint32_t* bxp = (uint32_t*)(ws + OFF_BXP);

    pack_w2_frag<<<400, 256, 0, stream>>>(w2, w2f);
    pack_conv_w<<<(128 * 9 + 255) / 256, 256, 0, stream>>>(w3, w3p, 9);
    pack_conv_w<<<(128 * 9 + 255) / 256, 256, 0, stream>>>(w4, w4p, 9);
    pack_fc_w<<<2, 256, 0, stream>>>(wfc, fcp);

    conv1_csum<<<BATCH * 8, 256, 0, stream>>>(x, w1, csum);
    conv1_tree<<<BATCH, 128, 0, stream>>>(csum, mean1, zcnt);
    conv1_bin<<<BATCH * 4, 256, 0, stream>>>(x, w1, mean1, b1p, zcnt, zlist);

    bconv2_mfma<<<BATCH * 12, 128, 0, stream>>>(b1p, (const uint8_t*)w2f, h2, zcnt, zlist);
    npmean_bin_kernel<144, 256, 144, 72, 72, 0><<<BATCH, 256, 0, stream>>>(h2, a2, b2p);

    bconv3_kernel<<<BATCH * 2, 256, 0, stream>>>(b2p, w3p, h3);
    npmean_bin_kernel<100, 128, 200, 96, 104, 0><<<BATCH, 256, 0, stream>>>(h3, a3, b3p);

    bconv4_kernel<<<BATCH, 256, 0, stream>>>(b3p, w4p, h4);
    npmean_bin_kernel<16, 16, 256, 128, 128, 1><<<BATCH, 256, 0, stream>>>(h4, a4, bxp);

    fc_kernel<<<BATCH, 256, 0, stream>>>(bxp, fcp, bfc, afc, out);
}